// Round 1
// baseline (1534.909 us; speedup 1.0000x reference)
//
#include <hip/hip_runtime.h>
#include <hip/hip_bf16.h>
#include <cstdint>
#include <cstddef>

// Problem constants (match reference)
#define NN      50000
#define IN_C    512
#define EE      800000
#define ETOT    850000      // E + N self-loops
#define HH      2
#define CC      64
#define HC      128
#define BB      64
#define OUTC    2
#define NEG_SLOPE 0.2f
#define BN_EPS  1e-5f

// ---------- helpers ----------
__device__ __forceinline__ unsigned fenc(float f) {
    unsigned u = __float_as_uint(f);
    return (u & 0x80000000u) ? ~u : (u | 0x80000000u);
}
__device__ __forceinline__ float fdec(unsigned u) {
    return (u & 0x80000000u) ? __uint_as_float(u ^ 0x80000000u)
                             : __uint_as_float(~u);
}
__device__ __forceinline__ void edge_sd(const int* __restrict__ ei, int e, int& s, int& d) {
    if (e < EE) { s = ei[e]; d = ei[EE + e]; }
    else        { s = e - EE; d = e - EE; }
}

// ---------- GEMM: C[N,128] = f(A[N,K]) @ W[K,128]; f = optional BN-affine+ReLU ----------
template<bool AFFINE>
__global__ __launch_bounds__(256) void gemm_kernel(
    const float* __restrict__ A, const float* __restrict__ W,
    float* __restrict__ Cout, int Nrows, int K,
    const float* __restrict__ sc, const float* __restrict__ sh)
{
    constexpr int BM = 64, BK = 32;
    __shared__ float As[BK][BM + 1];
    __shared__ float Bs[BK][HC];
    const int tid = threadIdx.x;
    const int m0 = blockIdx.x * BM;
    const int ty = tid >> 4, tx = tid & 15;

    float acc[4][8];
#pragma unroll
    for (int i = 0; i < 4; ++i)
#pragma unroll
        for (int j = 0; j < 8; ++j) acc[i][j] = 0.f;

    for (int k0 = 0; k0 < K; k0 += BK) {
        // A tile: 64 rows x 32 k  (2 float4 per thread)
#pragma unroll
        for (int l = 0; l < 2; ++l) {
            int lin = tid + l * 256;
            int m = lin >> 3;
            int k4 = (lin & 7) << 2;
            float4 v = make_float4(0.f, 0.f, 0.f, 0.f);
            if (m0 + m < Nrows)
                v = *(const float4*)&A[(size_t)(m0 + m) * K + k0 + k4];
            if (AFFINE) {
                v.x = fmaxf(fmaf(sc[k0+k4+0], v.x, sh[k0+k4+0]), 0.f);
                v.y = fmaxf(fmaf(sc[k0+k4+1], v.y, sh[k0+k4+1]), 0.f);
                v.z = fmaxf(fmaf(sc[k0+k4+2], v.z, sh[k0+k4+2]), 0.f);
                v.w = fmaxf(fmaf(sc[k0+k4+3], v.w, sh[k0+k4+3]), 0.f);
            }
            As[k4+0][m] = v.x; As[k4+1][m] = v.y;
            As[k4+2][m] = v.z; As[k4+3][m] = v.w;
        }
        // B tile: 32 k x 128 c (4 float4 per thread)
#pragma unroll
        for (int l = 0; l < 4; ++l) {
            int lin = tid + l * 256;
            int k = lin >> 5;
            int c4 = (lin & 31) << 2;
            *(float4*)&Bs[k][c4] = *(const float4*)&W[(size_t)(k0 + k) * HC + c4];
        }
        __syncthreads();
#pragma unroll
        for (int k = 0; k < BK; ++k) {
            float aa[4];
#pragma unroll
            for (int i = 0; i < 4; ++i) aa[i] = As[k][ty * 4 + i];
            float4 b0 = *(float4*)&Bs[k][tx * 8];
            float4 b1 = *(float4*)&Bs[k][tx * 8 + 4];
            float bb[8] = {b0.x, b0.y, b0.z, b0.w, b1.x, b1.y, b1.z, b1.w};
#pragma unroll
            for (int i = 0; i < 4; ++i)
#pragma unroll
                for (int j = 0; j < 8; ++j)
                    acc[i][j] = fmaf(aa[i], bb[j], acc[i][j]);
        }
        __syncthreads();
    }
#pragma unroll
    for (int i = 0; i < 4; ++i) {
        int m = m0 + ty * 4 + i;
        if (m < Nrows) {
            *(float4*)&Cout[(size_t)m * HC + tx * 8]     = make_float4(acc[i][0], acc[i][1], acc[i][2], acc[i][3]);
            *(float4*)&Cout[(size_t)m * HC + tx * 8 + 4] = make_float4(acc[i][4], acc[i][5], acc[i][6], acc[i][7]);
        }
    }
}

// ---------- per-node attention logits: one wave per node ----------
__global__ __launch_bounds__(256) void alpha_kernel(
    const float* __restrict__ h, const float* __restrict__ att_s,
    const float* __restrict__ att_d, float* __restrict__ as_, float* __restrict__ ad_)
{
    int wave = (blockIdx.x * 256 + threadIdx.x) >> 6;
    int lane = threadIdx.x & 63;
    if (wave >= NN) return;
    float h0 = h[(size_t)wave * HC + lane];
    float h1 = h[(size_t)wave * HC + 64 + lane];
    float s0 = h0 * att_s[lane],      s1 = h1 * att_s[64 + lane];
    float d0 = h0 * att_d[lane],      d1 = h1 * att_d[64 + lane];
#pragma unroll
    for (int o = 32; o > 0; o >>= 1) {
        s0 += __shfl_down(s0, o); s1 += __shfl_down(s1, o);
        d0 += __shfl_down(d0, o); d1 += __shfl_down(d1, o);
    }
    if (lane == 0) {
        as_[wave * 2 + 0] = s0; as_[wave * 2 + 1] = s1;
        ad_[wave * 2 + 0] = d0; ad_[wave * 2 + 1] = d1;
    }
}

// ---------- edge pass A: segment max (encoded uint atomicMax) ----------
__global__ __launch_bounds__(256) void edge_max_kernel(
    const int* __restrict__ ei, const float* __restrict__ as_,
    const float* __restrict__ ad_, unsigned* __restrict__ menc)
{
    int e = blockIdx.x * 256 + threadIdx.x;
    if (e >= ETOT) return;
    int s, d; edge_sd(ei, e, s, d);
    float2 a = *(const float2*)&as_[s * 2];
    float2 b = *(const float2*)&ad_[d * 2];
    float v0 = a.x + b.x; v0 = v0 > 0.f ? v0 : NEG_SLOPE * v0;
    float v1 = a.y + b.y; v1 = v1 > 0.f ? v1 : NEG_SLOPE * v1;
    atomicMax(&menc[d * 2 + 0], fenc(v0));
    atomicMax(&menc[d * 2 + 1], fenc(v1));
}

__global__ __launch_bounds__(256) void m_decode_kernel(unsigned* __restrict__ menc)
{
    int i = blockIdx.x * 256 + threadIdx.x;
    if (i >= NN * HH) return;
    float f = fdec(menc[i]);
    ((float*)menc)[i] = f;
}

// ---------- edge pass B: exp & denom ----------
__global__ __launch_bounds__(256) void edge_expsum_kernel(
    const int* __restrict__ ei, const float* __restrict__ as_,
    const float* __restrict__ ad_, const float* __restrict__ m,
    float* __restrict__ den)
{
    int e = blockIdx.x * 256 + threadIdx.x;
    if (e >= ETOT) return;
    int s, d; edge_sd(ei, e, s, d);
    float2 a = *(const float2*)&as_[s * 2];
    float2 b = *(const float2*)&ad_[d * 2];
    float v0 = a.x + b.x; v0 = v0 > 0.f ? v0 : NEG_SLOPE * v0;
    float v1 = a.y + b.y; v1 = v1 > 0.f ? v1 : NEG_SLOPE * v1;
    float e0 = __expf(v0 - m[d * 2 + 0]);
    float e1 = __expf(v1 - m[d * 2 + 1]);
    atomicAdd(&den[d * 2 + 0], e0);
    atomicAdd(&den[d * 2 + 1], e1);
}

// ---------- edge pass C: weighted aggregate (1 thread per edge-channel) ----------
__global__ __launch_bounds__(256) void edge_agg_kernel(
    const int* __restrict__ ei, const float* __restrict__ as_,
    const float* __restrict__ ad_, const float* __restrict__ m,
    const float* __restrict__ den, const float* __restrict__ h,
    float* __restrict__ out)
{
    int tid = blockIdx.x * 256 + threadIdx.x;
    int e = tid >> 7;
    if (e >= ETOT) return;
    int c = tid & 127;
    int hd = c >> 6;
    int s, d; edge_sd(ei, e, s, d);
    float v = as_[s * 2 + hd] + ad_[d * 2 + hd];
    v = v > 0.f ? v : NEG_SLOPE * v;
    float ex = __expf(v - m[d * 2 + hd]);
    float alpha = ex / den[d * 2 + hd];
    float val = h[(size_t)s * HC + c] * alpha;
    atomicAdd(&out[(size_t)d * HC + c], val);
}

// ---------- BN stats ----------
__global__ __launch_bounds__(256) void bn_stats_kernel(
    const float* __restrict__ x, float* __restrict__ stats)
{
    int c = threadIdx.x & 127;
    int half = threadIdx.x >> 7;
    float s = 0.f, sq = 0.f;
    for (int r = blockIdx.x * 2 + half; r < NN; r += gridDim.x * 2) {
        float v = x[(size_t)r * HC + c];
        s += v; sq += v * v;
    }
    __shared__ float ls[256], lq[256];
    ls[threadIdx.x] = s; lq[threadIdx.x] = sq;
    __syncthreads();
    if (half == 0) {
        s += ls[threadIdx.x + 128];
        sq += lq[threadIdx.x + 128];
        atomicAdd(&stats[c], s);
        atomicAdd(&stats[128 + c], sq);
    }
}

__global__ void bn_params_kernel(
    const float* __restrict__ stats, const float* __restrict__ gamma,
    const float* __restrict__ beta, float* __restrict__ sc, float* __restrict__ sh)
{
    int c = threadIdx.x;
    const float inv_n = 1.0f / (float)NN;
    float mu = stats[c] * inv_n;
    float var = stats[128 + c] * inv_n - mu * mu;
    float rs = rsqrtf(var + BN_EPS);
    float s = gamma[c] * rs;
    sc[c] = s;
    sh[c] = beta[c] - mu * s;
}

// ---------- pool (batch sorted -> running accumulation, flush on change) ----------
__global__ __launch_bounds__(256) void pool_kernel(
    const float* __restrict__ x, const float* __restrict__ sc,
    const float* __restrict__ sh, const int* __restrict__ batch,
    float* __restrict__ pool, float* __restrict__ cnt)
{
    int c = threadIdx.x & 127;
    int half = threadIdx.x >> 7;
    int r0 = blockIdx.x * 512;
    int rend = min(r0 + 512, NN);
    float s = sc[c], b = sh[c];
    int cur = -1; float acc = 0.f, ccount = 0.f;
    for (int r = r0 + half; r < rend; r += 2) {
        int g = batch[r];
        if (g != cur) {
            if (cur >= 0) {
                atomicAdd(&pool[cur * HC + c], acc);
                if (c == 0) atomicAdd(&cnt[cur], ccount);
            }
            cur = g; acc = 0.f; ccount = 0.f;
        }
        float v = x[(size_t)r * HC + c];
        acc += fmaxf(fmaf(s, v, b), 0.f);
        ccount += 1.f;
    }
    if (cur >= 0) {
        atomicAdd(&pool[cur * HC + c], acc);
        if (c == 0) atomicAdd(&cnt[cur], ccount);
    }
}

// ---------- final linear: [64,128]@[128,2] + blin ----------
__global__ void final_kernel(
    const float* __restrict__ pool, const float* __restrict__ cnt,
    const float* __restrict__ Wlin, const float* __restrict__ blin,
    float* __restrict__ outp)
{
    int t = threadIdx.x;               // 128 threads
    int b = t >> 1, oc = t & 1;
    float inv = 1.f / fmaxf(cnt[b], 1.f);
    float s = blin[oc];
    for (int c = 0; c < HC; ++c)
        s += pool[b * HC + c] * inv * Wlin[c * 2 + oc];
    outp[b * 2 + oc] = s;
}

// ---------- workspace layout (floats) ----------
static constexpr size_t OFF_H     = 0;                       // [N*HC]
static constexpr size_t OFF_OUT   = OFF_H   + (size_t)NN*HC; // [N*HC]
static constexpr size_t OFF_AS    = OFF_OUT + (size_t)NN*HC; // [N*H]
static constexpr size_t OFF_AD    = OFF_AS  + (size_t)NN*HH;
static constexpr size_t OFF_M1    = OFF_AD  + (size_t)NN*HH; // zero from here
static constexpr size_t OFF_DEN1  = OFF_M1  + (size_t)NN*HH;
static constexpr size_t OFF_M2    = OFF_DEN1+ (size_t)NN*HH;
static constexpr size_t OFF_DEN2  = OFF_M2  + (size_t)NN*HH;
static constexpr size_t OFF_ST1   = OFF_DEN2+ (size_t)NN*HH; // [256]
static constexpr size_t OFF_ST2   = OFF_ST1 + 256;
static constexpr size_t OFF_SC1   = OFF_ST2 + 256;           // [128]
static constexpr size_t OFF_SH1   = OFF_SC1 + 128;
static constexpr size_t OFF_SC2   = OFF_SH1 + 128;
static constexpr size_t OFF_SH2   = OFF_SC2 + 128;
static constexpr size_t OFF_POOL  = OFF_SH2 + 128;           // [B*HC]
static constexpr size_t OFF_CNT   = OFF_POOL+ (size_t)BB*HC; // [B]
static constexpr size_t OFF_END   = OFF_CNT + BB;

extern "C" void kernel_launch(void* const* d_in, const int* in_sizes, int n_in,
                              void* d_out, int out_size, void* d_ws, size_t ws_size,
                              hipStream_t stream)
{
    const float* x       = (const float*)d_in[0];
    const int*   ei      = (const int*)  d_in[1];
    const int*   batch   = (const int*)  d_in[2];
    const float* W1      = (const float*)d_in[3];
    const float* atts1   = (const float*)d_in[4];
    const float* attd1   = (const float*)d_in[5];
    const float* gamma1  = (const float*)d_in[7];
    const float* beta1   = (const float*)d_in[8];
    const float* W2      = (const float*)d_in[9];
    const float* atts2   = (const float*)d_in[10];
    const float* attd2   = (const float*)d_in[11];
    const float* gamma2  = (const float*)d_in[13];
    const float* beta2   = (const float*)d_in[14];
    const float* Wlin    = (const float*)d_in[15];
    const float* blin    = (const float*)d_in[16];
    float* outp = (float*)d_out;

    float* ws    = (float*)d_ws;
    float* h     = ws + OFF_H;
    float* out   = ws + OFF_OUT;
    float* as_   = ws + OFF_AS;
    float* ad_   = ws + OFF_AD;
    float* m1    = ws + OFF_M1;
    float* den1  = ws + OFF_DEN1;
    float* m2    = ws + OFF_M2;
    float* den2  = ws + OFF_DEN2;
    float* st1   = ws + OFF_ST1;
    float* st2   = ws + OFF_ST2;
    float* sc1   = ws + OFF_SC1;
    float* sh1   = ws + OFF_SH1;
    float* sc2   = ws + OFF_SC2;
    float* sh2   = ws + OFF_SH2;
    float* pool  = ws + OFF_POOL;
    float* cnt   = ws + OFF_CNT;

    const int EDGE_BLK  = (ETOT + 255) / 256;
    const int AGG_BLK   = (int)(((size_t)ETOT * HC) / 256);   // exact: 425000
    const int GEMM_BLK  = (NN + 63) / 64;
    const int ALPHA_BLK = (NN + 3) / 4;
    const int DEC_BLK   = (NN * HH + 255) / 256;
    const int POOL_BLK  = (NN + 511) / 512;

    // zero accumulators: out, then [m1 .. end]
    hipMemsetAsync(out, 0, (size_t)NN * HC * sizeof(float), stream);
    hipMemsetAsync(m1, 0, (OFF_END - OFF_M1) * sizeof(float), stream);

    // ----- layer 1 -----
    gemm_kernel<false><<<GEMM_BLK, 256, 0, stream>>>(x, W1, h, NN, IN_C, nullptr, nullptr);
    alpha_kernel<<<ALPHA_BLK, 256, 0, stream>>>(h, atts1, attd1, as_, ad_);
    edge_max_kernel<<<EDGE_BLK, 256, 0, stream>>>(ei, as_, ad_, (unsigned*)m1);
    m_decode_kernel<<<DEC_BLK, 256, 0, stream>>>((unsigned*)m1);
    edge_expsum_kernel<<<EDGE_BLK, 256, 0, stream>>>(ei, as_, ad_, m1, den1);
    edge_agg_kernel<<<AGG_BLK, 256, 0, stream>>>(ei, as_, ad_, m1, den1, h, out);
    bn_stats_kernel<<<512, 256, 0, stream>>>(out, st1);
    bn_params_kernel<<<1, 128, 0, stream>>>(st1, gamma1, beta1, sc1, sh1);

    // ----- layer 2 (BN1-affine+ReLU fused into GEMM2 A-load) -----
    gemm_kernel<true><<<GEMM_BLK, 256, 0, stream>>>(out, W2, h, NN, HC, sc1, sh1);
    hipMemsetAsync(out, 0, (size_t)NN * HC * sizeof(float), stream);
    alpha_kernel<<<ALPHA_BLK, 256, 0, stream>>>(h, atts2, attd2, as_, ad_);
    edge_max_kernel<<<EDGE_BLK, 256, 0, stream>>>(ei, as_, ad_, (unsigned*)m2);
    m_decode_kernel<<<DEC_BLK, 256, 0, stream>>>((unsigned*)m2);
    edge_expsum_kernel<<<EDGE_BLK, 256, 0, stream>>>(ei, as_, ad_, m2, den2);
    edge_agg_kernel<<<AGG_BLK, 256, 0, stream>>>(ei, as_, ad_, m2, den2, h, out);
    bn_stats_kernel<<<512, 256, 0, stream>>>(out, st2);
    bn_params_kernel<<<1, 128, 0, stream>>>(st2, gamma2, beta2, sc2, sh2);

    // ----- pool + final linear -----
    pool_kernel<<<POOL_BLK, 256, 0, stream>>>(out, sc2, sh2, batch, pool, cnt);
    final_kernel<<<1, 128, 0, stream>>>(pool, cnt, Wlin, blin, outp);
}

// Round 2
// 792.022 us; speedup vs baseline: 1.9380x; 1.9380x over previous
//
#include <hip/hip_runtime.h>
#include <hip/hip_bf16.h>
#include <cstdint>
#include <cstddef>

// Problem constants (match reference)
#define NN      50000
#define IN_C    512
#define EE      800000
#define ETOT    850000      // E + N self-loops
#define HH      2
#define CC      64
#define HC      128
#define BB      64
#define OUTC    2
#define NEG_SLOPE 0.2f
#define BN_EPS  1e-5f

__device__ __forceinline__ void edge_sd(const int* __restrict__ ei, int e, int& s, int& d) {
    if (e < EE) { s = ei[e]; d = ei[EE + e]; }
    else        { s = e - EE; d = e - EE; }
}

// ================= CSR build (graph is fixed; built once per launch, reused by both layers) =================
__global__ __launch_bounds__(256) void deg_kernel(const int* __restrict__ ei, int* __restrict__ deg)
{
    int e = blockIdx.x * 256 + threadIdx.x;
    if (e >= ETOT) return;
    int d = (e < EE) ? ei[EE + e] : (e - EE);
    atomicAdd(&deg[d], 1);
}

#define SCAN_T 1024
__global__ __launch_bounds__(SCAN_T) void scan_kernel(
    const int* __restrict__ deg, int* __restrict__ rowp, int* __restrict__ cur)
{
    __shared__ int part[SCAN_T];
    int t = threadIdx.x;
    const int per = (NN + SCAN_T - 1) / SCAN_T;   // 49
    int b = t * per, e = min(b + per, NN);
    int s = 0;
    for (int i = b; i < e; ++i) s += deg[i];
    part[t] = s;
    __syncthreads();
    for (int off = 1; off < SCAN_T; off <<= 1) {
        int v = (t >= off) ? part[t - off] : 0;
        __syncthreads();
        part[t] += v;
        __syncthreads();
    }
    int run = (t == 0) ? 0 : part[t - 1];
    for (int i = b; i < e; ++i) {
        rowp[i] = run; cur[i] = run;
        run += deg[i];
    }
    if (t == SCAN_T - 1) rowp[NN] = run;          // == ETOT
}

__global__ __launch_bounds__(256) void scatter_kernel(
    const int* __restrict__ ei, int* __restrict__ cur, int* __restrict__ esrc)
{
    int e = blockIdx.x * 256 + threadIdx.x;
    if (e >= ETOT) return;
    int s, d; edge_sd(ei, e, s, d);
    int pos = atomicAdd(&cur[d], 1);
    esrc[pos] = s;
}

// ================= GEMM: C[N,128] = f(A[N,K]) @ W[K,128]; f = optional BN-affine+ReLU =================
template<bool AFFINE>
__global__ __launch_bounds__(256) void gemm_kernel(
    const float* __restrict__ A, const float* __restrict__ W,
    float* __restrict__ Cout, int Nrows, int K,
    const float* __restrict__ sc, const float* __restrict__ sh)
{
    constexpr int BM = 64, BK = 32;
    __shared__ float As[BK][BM + 1];
    __shared__ float Bs[BK][HC];
    const int tid = threadIdx.x;
    const int m0 = blockIdx.x * BM;
    const int ty = tid >> 4, tx = tid & 15;

    float acc[4][8];
#pragma unroll
    for (int i = 0; i < 4; ++i)
#pragma unroll
        for (int j = 0; j < 8; ++j) acc[i][j] = 0.f;

    for (int k0 = 0; k0 < K; k0 += BK) {
#pragma unroll
        for (int l = 0; l < 2; ++l) {
            int lin = tid + l * 256;
            int m = lin >> 3;
            int k4 = (lin & 7) << 2;
            float4 v = make_float4(0.f, 0.f, 0.f, 0.f);
            if (m0 + m < Nrows)
                v = *(const float4*)&A[(size_t)(m0 + m) * K + k0 + k4];
            if (AFFINE) {
                v.x = fmaxf(fmaf(sc[k0+k4+0], v.x, sh[k0+k4+0]), 0.f);
                v.y = fmaxf(fmaf(sc[k0+k4+1], v.y, sh[k0+k4+1]), 0.f);
                v.z = fmaxf(fmaf(sc[k0+k4+2], v.z, sh[k0+k4+2]), 0.f);
                v.w = fmaxf(fmaf(sc[k0+k4+3], v.w, sh[k0+k4+3]), 0.f);
            }
            As[k4+0][m] = v.x; As[k4+1][m] = v.y;
            As[k4+2][m] = v.z; As[k4+3][m] = v.w;
        }
#pragma unroll
        for (int l = 0; l < 4; ++l) {
            int lin = tid + l * 256;
            int k = lin >> 5;
            int c4 = (lin & 31) << 2;
            *(float4*)&Bs[k][c4] = *(const float4*)&W[(size_t)(k0 + k) * HC + c4];
        }
        __syncthreads();
#pragma unroll
        for (int k = 0; k < BK; ++k) {
            float aa[4];
#pragma unroll
            for (int i = 0; i < 4; ++i) aa[i] = As[k][ty * 4 + i];
            float4 b0 = *(float4*)&Bs[k][tx * 8];
            float4 b1 = *(float4*)&Bs[k][tx * 8 + 4];
            float bb[8] = {b0.x, b0.y, b0.z, b0.w, b1.x, b1.y, b1.z, b1.w};
#pragma unroll
            for (int i = 0; i < 4; ++i)
#pragma unroll
                for (int j = 0; j < 8; ++j)
                    acc[i][j] = fmaf(aa[i], bb[j], acc[i][j]);
        }
        __syncthreads();
    }
#pragma unroll
    for (int i = 0; i < 4; ++i) {
        int m = m0 + ty * 4 + i;
        if (m < Nrows) {
            *(float4*)&Cout[(size_t)m * HC + tx * 8]     = make_float4(acc[i][0], acc[i][1], acc[i][2], acc[i][3]);
            *(float4*)&Cout[(size_t)m * HC + tx * 8 + 4] = make_float4(acc[i][4], acc[i][5], acc[i][6], acc[i][7]);
        }
    }
}

// ================= per-node attention logits: one wave per node =================
__global__ __launch_bounds__(256) void alpha_kernel(
    const float* __restrict__ h, const float* __restrict__ att_s,
    const float* __restrict__ att_d, float* __restrict__ as_, float* __restrict__ ad_)
{
    int wave = (blockIdx.x * 256 + threadIdx.x) >> 6;
    int lane = threadIdx.x & 63;
    if (wave >= NN) return;
    float h0 = h[(size_t)wave * HC + lane];
    float h1 = h[(size_t)wave * HC + 64 + lane];
    float s0 = h0 * att_s[lane],      s1 = h1 * att_s[64 + lane];
    float d0 = h0 * att_d[lane],      d1 = h1 * att_d[64 + lane];
#pragma unroll
    for (int o = 32; o > 0; o >>= 1) {
        s0 += __shfl_down(s0, o); s1 += __shfl_down(s1, o);
        d0 += __shfl_down(d0, o); d1 += __shfl_down(d1, o);
    }
    if (lane == 0) {
        as_[wave * 2 + 0] = s0; as_[wave * 2 + 1] = s1;
        ad_[wave * 2 + 0] = d0; ad_[wave * 2 + 1] = d1;
    }
}

// ================= fused segment-softmax + aggregate: one wave per dst node =================
// lane owns channels (lane) [head0] and (lane+64) [head1]; online softmax in registers.
__global__ __launch_bounds__(256) void gat_agg_kernel(
    const int* __restrict__ rowp, const int* __restrict__ esrc,
    const float* __restrict__ as_, const float* __restrict__ ad_,
    const float* __restrict__ h, float* __restrict__ out)
{
    int node = (blockIdx.x * 256 + threadIdx.x) >> 6;
    int lane = threadIdx.x & 63;
    if (node >= NN) return;
    int beg = rowp[node], end = rowp[node + 1];
    float ad0 = ad_[node * 2 + 0], ad1 = ad_[node * 2 + 1];

    float m0 = -3.0e38f, m1 = -3.0e38f;
    float l0 = 0.f, l1 = 0.f, a0 = 0.f, a1 = 0.f;

    for (int j0 = beg; j0 < end; j0 += 64) {
        int nj = min(64, end - j0);
        int   sl  = 0;
        float es0 = 0.f, es1 = 0.f;
        if (j0 + lane < end) {
            sl = esrc[j0 + lane];
            float2 t = *(const float2*)&as_[sl * 2];
            es0 = t.x; es1 = t.y;
        }
        for (int j = 0; j < nj; ++j) {
            int   s  = __shfl(sl, j);
            float e0 = __shfl(es0, j) + ad0; e0 = e0 > 0.f ? e0 : NEG_SLOPE * e0;
            float e1 = __shfl(es1, j) + ad1; e1 = e1 > 0.f ? e1 : NEG_SLOPE * e1;
            float h0 = h[(size_t)s * HC + lane];
            float h1 = h[(size_t)s * HC + 64 + lane];
            float nm0 = fmaxf(m0, e0), nm1 = fmaxf(m1, e1);
            float sc0 = __expf(m0 - nm0), sc1 = __expf(m1 - nm1);
            float p0  = __expf(e0 - nm0), p1  = __expf(e1 - nm1);
            l0 = fmaf(l0, sc0, p0);       l1 = fmaf(l1, sc1, p1);
            a0 = fmaf(a0, sc0, p0 * h0);  a1 = fmaf(a1, sc1, p1 * h1);
            m0 = nm0; m1 = nm1;
        }
    }
    out[(size_t)node * HC + lane]      = a0 / l0;
    out[(size_t)node * HC + 64 + lane] = a1 / l1;
}

// ================= BN stats =================
__global__ __launch_bounds__(256) void bn_stats_kernel(
    const float* __restrict__ x, float* __restrict__ stats)
{
    int c = threadIdx.x & 127;
    int half = threadIdx.x >> 7;
    float s = 0.f, sq = 0.f;
    for (int r = blockIdx.x * 2 + half; r < NN; r += gridDim.x * 2) {
        float v = x[(size_t)r * HC + c];
        s += v; sq += v * v;
    }
    __shared__ float ls[256], lq[256];
    ls[threadIdx.x] = s; lq[threadIdx.x] = sq;
    __syncthreads();
    if (half == 0) {
        s += ls[threadIdx.x + 128];
        sq += lq[threadIdx.x + 128];
        atomicAdd(&stats[c], s);
        atomicAdd(&stats[128 + c], sq);
    }
}

__global__ void bn_params_kernel(
    const float* __restrict__ stats, const float* __restrict__ gamma,
    const float* __restrict__ beta, float* __restrict__ sc, float* __restrict__ sh)
{
    int c = threadIdx.x;
    const float inv_n = 1.0f / (float)NN;
    float mu = stats[c] * inv_n;
    float var = stats[128 + c] * inv_n - mu * mu;
    float rs = rsqrtf(var + BN_EPS);
    float s = gamma[c] * rs;
    sc[c] = s;
    sh[c] = beta[c] - mu * s;
}

// ================= pool (batch sorted -> running accumulation, flush on change) =================
__global__ __launch_bounds__(256) void pool_kernel(
    const float* __restrict__ x, const float* __restrict__ sc,
    const float* __restrict__ sh, const int* __restrict__ batch,
    float* __restrict__ pool, float* __restrict__ cnt)
{
    int c = threadIdx.x & 127;
    int half = threadIdx.x >> 7;
    int r0 = blockIdx.x * 512;
    int rend = min(r0 + 512, NN);
    float s = sc[c], b = sh[c];
    int cur = -1; float acc = 0.f, ccount = 0.f;
    for (int r = r0 + half; r < rend; r += 2) {
        int g = batch[r];
        if (g != cur) {
            if (cur >= 0) {
                atomicAdd(&pool[cur * HC + c], acc);
                if (c == 0) atomicAdd(&cnt[cur], ccount);
            }
            cur = g; acc = 0.f; ccount = 0.f;
        }
        float v = x[(size_t)r * HC + c];
        acc += fmaxf(fmaf(s, v, b), 0.f);
        ccount += 1.f;
    }
    if (cur >= 0) {
        atomicAdd(&pool[cur * HC + c], acc);
        if (c == 0) atomicAdd(&cnt[cur], ccount);
    }
}

// ================= final linear: [64,128]@[128,2] + blin =================
__global__ void final_kernel(
    const float* __restrict__ pool, const float* __restrict__ cnt,
    const float* __restrict__ Wlin, const float* __restrict__ blin,
    float* __restrict__ outp)
{
    int t = threadIdx.x;               // 128 threads
    int b = t >> 1, oc = t & 1;
    float inv = 1.f / fmaxf(cnt[b], 1.f);
    float s = blin[oc];
    for (int c = 0; c < HC; ++c)
        s += pool[b * HC + c] * inv * Wlin[c * 2 + oc];
    outp[b * 2 + oc] = s;
}

// ================= workspace layout =================
// floats
static constexpr size_t OFF_H     = 0;                        // [N*HC]
static constexpr size_t OFF_OUT   = OFF_H   + (size_t)NN*HC;  // [N*HC]
static constexpr size_t OFF_AS    = OFF_OUT + (size_t)NN*HC;  // [N*2]
static constexpr size_t OFF_AD    = OFF_AS  + (size_t)NN*HH;
static constexpr size_t OFF_ST1   = OFF_AD  + (size_t)NN*HH;  // zero from here: [256]
static constexpr size_t OFF_ST2   = OFF_ST1 + 256;
static constexpr size_t OFF_SC1   = OFF_ST2 + 256;            // [128]
static constexpr size_t OFF_SH1   = OFF_SC1 + 128;
static constexpr size_t OFF_SC2   = OFF_SH1 + 128;
static constexpr size_t OFF_SH2   = OFF_SC2 + 128;
static constexpr size_t OFF_POOL  = OFF_SH2 + 128;            // [B*HC]
static constexpr size_t OFF_CNT   = OFF_POOL+ (size_t)BB*HC;  // [B]
static constexpr size_t OFF_ZEND  = OFF_CNT + BB;             // end of zeroed float region
// ints (after float region)
static constexpr size_t IOFF_DEG  = 0;                        // [N]  (zeroed)
static constexpr size_t IOFF_ROWP = IOFF_DEG  + NN;           // [N+1]
static constexpr size_t IOFF_CUR  = IOFF_ROWP + NN + 1;       // [N]
static constexpr size_t IOFF_ESRC = IOFF_CUR  + NN;           // [ETOT]

extern "C" void kernel_launch(void* const* d_in, const int* in_sizes, int n_in,
                              void* d_out, int out_size, void* d_ws, size_t ws_size,
                              hipStream_t stream)
{
    const float* x       = (const float*)d_in[0];
    const int*   ei      = (const int*)  d_in[1];
    const int*   batch   = (const int*)  d_in[2];
    const float* W1      = (const float*)d_in[3];
    const float* atts1   = (const float*)d_in[4];
    const float* attd1   = (const float*)d_in[5];
    const float* gamma1  = (const float*)d_in[7];
    const float* beta1   = (const float*)d_in[8];
    const float* W2      = (const float*)d_in[9];
    const float* atts2   = (const float*)d_in[10];
    const float* attd2   = (const float*)d_in[11];
    const float* gamma2  = (const float*)d_in[13];
    const float* beta2   = (const float*)d_in[14];
    const float* Wlin    = (const float*)d_in[15];
    const float* blin    = (const float*)d_in[16];
    float* outp = (float*)d_out;

    float* ws    = (float*)d_ws;
    float* h     = ws + OFF_H;
    float* out   = ws + OFF_OUT;
    float* as_   = ws + OFF_AS;
    float* ad_   = ws + OFF_AD;
    float* st1   = ws + OFF_ST1;
    float* st2   = ws + OFF_ST2;
    float* sc1   = ws + OFF_SC1;
    float* sh1   = ws + OFF_SH1;
    float* sc2   = ws + OFF_SC2;
    float* sh2   = ws + OFF_SH2;
    float* pool  = ws + OFF_POOL;
    float* cnt   = ws + OFF_CNT;

    int* iws  = (int*)(ws + OFF_ZEND);
    int* deg  = iws + IOFF_DEG;
    int* rowp = iws + IOFF_ROWP;
    int* curp = iws + IOFF_CUR;
    int* esrc = iws + IOFF_ESRC;

    const int EDGE_BLK  = (ETOT + 255) / 256;
    const int GEMM_BLK  = (NN + 63) / 64;
    const int WAVE_BLK  = (NN + 3) / 4;          // 1 wave per node, 4 waves/block
    const int POOL_BLK  = (NN + 511) / 512;

    // zero: bn-stats/pool/cnt float region + deg
    hipMemsetAsync(st1, 0, (OFF_ZEND - OFF_ST1) * sizeof(float), stream);
    hipMemsetAsync(deg, 0, NN * sizeof(int), stream);

    // ----- CSR build (dst-sorted; reused for both layers) -----
    deg_kernel<<<EDGE_BLK, 256, 0, stream>>>(ei, deg);
    scan_kernel<<<1, SCAN_T, 0, stream>>>(deg, rowp, curp);
    scatter_kernel<<<EDGE_BLK, 256, 0, stream>>>(ei, curp, esrc);

    // ----- layer 1 -----
    gemm_kernel<false><<<GEMM_BLK, 256, 0, stream>>>(x, W1, h, NN, IN_C, nullptr, nullptr);
    alpha_kernel<<<WAVE_BLK, 256, 0, stream>>>(h, atts1, attd1, as_, ad_);
    gat_agg_kernel<<<WAVE_BLK, 256, 0, stream>>>(rowp, esrc, as_, ad_, h, out);
    bn_stats_kernel<<<512, 256, 0, stream>>>(out, st1);
    bn_params_kernel<<<1, 128, 0, stream>>>(st1, gamma1, beta1, sc1, sh1);

    // ----- layer 2 (BN1-affine+ReLU fused into GEMM2 A-load) -----
    gemm_kernel<true><<<GEMM_BLK, 256, 0, stream>>>(out, W2, h, NN, HC, sc1, sh1);
    alpha_kernel<<<WAVE_BLK, 256, 0, stream>>>(h, atts2, attd2, as_, ad_);
    gat_agg_kernel<<<WAVE_BLK, 256, 0, stream>>>(rowp, esrc, as_, ad_, h, out);
    bn_stats_kernel<<<512, 256, 0, stream>>>(out, st2);
    bn_params_kernel<<<1, 128, 0, stream>>>(st2, gamma2, beta2, sc2, sh2);

    // ----- pool + final linear -----
    pool_kernel<<<POOL_BLK, 256, 0, stream>>>(out, sc2, sh2, batch, pool, cnt);
    final_kernel<<<1, 128, 0, stream>>>(pool, cnt, Wlin, blin, outp);
}

// Round 3
// 727.707 us; speedup vs baseline: 2.1092x; 1.0884x over previous
//
#include <hip/hip_runtime.h>
#include <hip/hip_bf16.h>
#include <cstdint>
#include <cstddef>

// Problem constants (match reference)
#define NN      50000
#define IN_C    512
#define EE      800000
#define ETOT    850000      // E + N self-loops
#define HH      2
#define CC      64
#define HC      128
#define BB      64
#define OUTC    2
#define NEG_SLOPE 0.2f
#define BN_EPS  1e-5f

typedef __bf16 bf16x8 __attribute__((ext_vector_type(8)));
typedef float  f32x4  __attribute__((ext_vector_type(4)));

__device__ __forceinline__ unsigned short f2bf(float f) {
    __bf16 b = (__bf16)f;                      // RNE convert
    return __builtin_bit_cast(unsigned short, b);
}

__device__ __forceinline__ void edge_sd(const int* __restrict__ ei, int e, int& s, int& d) {
    if (e < EE) { s = ei[e]; d = ei[EE + e]; }
    else        { s = e - EE; d = e - EE; }
}

// ================= CSR build (graph fixed; built once per launch, reused by both layers) =================
__global__ __launch_bounds__(256) void deg_kernel(const int* __restrict__ ei, int* __restrict__ deg)
{
    int e = blockIdx.x * 256 + threadIdx.x;
    if (e >= ETOT) return;
    int d = (e < EE) ? ei[EE + e] : (e - EE);
    atomicAdd(&deg[d], 1);
}

#define SCAN_T 1024
__global__ __launch_bounds__(SCAN_T) void scan_kernel(
    const int* __restrict__ deg, int* __restrict__ rowp, int* __restrict__ cur)
{
    __shared__ int part[SCAN_T];
    int t = threadIdx.x;
    const int per = (NN + SCAN_T - 1) / SCAN_T;   // 49
    int b = t * per, e = min(b + per, NN);
    int s = 0;
    for (int i = b; i < e; ++i) s += deg[i];
    part[t] = s;
    __syncthreads();
    for (int off = 1; off < SCAN_T; off <<= 1) {
        int v = (t >= off) ? part[t - off] : 0;
        __syncthreads();
        part[t] += v;
        __syncthreads();
    }
    int run = (t == 0) ? 0 : part[t - 1];
    for (int i = b; i < e; ++i) {
        rowp[i] = run; cur[i] = run;
        run += deg[i];
    }
    if (t == SCAN_T - 1) rowp[NN] = run;          // == ETOT
}

__global__ __launch_bounds__(256) void scatter_kernel(
    const int* __restrict__ ei, int* __restrict__ cur, int* __restrict__ esrc)
{
    int e = blockIdx.x * 256 + threadIdx.x;
    if (e >= ETOT) return;
    int s, d; edge_sd(ei, e, s, d);
    int pos = atomicAdd(&cur[d], 1);
    esrc[pos] = s;
}

// ================= W -> bf16 MFMA fragment order =================
// frag id = kblk*8 + ntile; lane holds B[k=kblk*32+quad*8+j][n=ntile*16+ln], j=0..7
// Wf[(frag*64 + lane)*8 + j]; a wave's frag read is 16B/lane fully coalesced.
__global__ __launch_bounds__(256) void wfrag_kernel(
    const float* __restrict__ W, unsigned short* __restrict__ Wf, int K)
{
    int t = blockIdx.x * 256 + threadIdx.x;       // t = frag*64 + lane
    if (t >= K * 16) return;                      // (K/32)*8*64 == K*16
    int lane = t & 63, frag = t >> 6;
    int kblk = frag >> 3, nt = frag & 7;
    int quad = lane >> 4, ln = lane & 15;
    int kbase = kblk * 32 + quad * 8;
    int n = nt * 16 + ln;
    unsigned short u[8];
#pragma unroll
    for (int j = 0; j < 8; ++j)
        u[j] = f2bf(W[(size_t)(kbase + j) * HC + n]);
    ushort4 a; a.x = u[0]; a.y = u[1]; a.z = u[2]; a.w = u[3];
    ushort4 b; b.x = u[4]; b.y = u[5]; b.z = u[6]; b.w = u[7];
    *(ushort4*)(Wf + (size_t)t * 8)     = a;
    *(ushort4*)(Wf + (size_t)t * 8 + 4) = b;
}

// ================= MFMA GEMM: C[N,128] = f(A[N,K]) @ W[K,128] =================
// BM=64, BK=32; 4 waves/block, wave w computes rows [w*16, w*16+16) x 128 cols.
// A staged fp32->bf16 into LDS (row stride 40 ushorts: +8 pad -> 2-way bank alias, free).
// B frags read from pre-packed Wf (L2-resident, 16B/lane coalesced).
template<bool AFFINE>
__global__ __launch_bounds__(256) void mfma_gemm_kernel(
    const float* __restrict__ A, const unsigned short* __restrict__ Wf,
    float* __restrict__ Cout, int K,
    const float* __restrict__ sc, const float* __restrict__ sh)
{
    __shared__ unsigned short As[64 * 40];
    const int tid  = threadIdx.x;
    const int wave = tid >> 6, lane = tid & 63;
    const int quad = lane >> 4, ln = lane & 15;
    const int m0 = blockIdx.x * 64;

    f32x4 acc[8];
#pragma unroll
    for (int nt = 0; nt < 8; ++nt) acc[nt] = (f32x4){0.f, 0.f, 0.f, 0.f};

    const int nsteps = K >> 5;
    for (int ks = 0; ks < nsteps; ++ks) {
        // stage A tile: 64 rows x 32 k, fp32 -> bf16
#pragma unroll
        for (int l = 0; l < 2; ++l) {
            int f  = tid + l * 256;               // 0..511
            int r  = f >> 3;                      // 0..63
            int k4 = (f & 7) << 2;                // 0,4,...,28
            int row = m0 + r;
            float4 v = make_float4(0.f, 0.f, 0.f, 0.f);
            if (row < NN) v = *(const float4*)&A[(size_t)row * K + ks * 32 + k4];
            if (AFFINE) {
                int kk = ks * 32 + k4;
                v.x = fmaxf(fmaf(sc[kk+0], v.x, sh[kk+0]), 0.f);
                v.y = fmaxf(fmaf(sc[kk+1], v.y, sh[kk+1]), 0.f);
                v.z = fmaxf(fmaf(sc[kk+2], v.z, sh[kk+2]), 0.f);
                v.w = fmaxf(fmaf(sc[kk+3], v.w, sh[kk+3]), 0.f);
            }
            ushort4 u; u.x = f2bf(v.x); u.y = f2bf(v.y); u.z = f2bf(v.z); u.w = f2bf(v.w);
            *(ushort4*)&As[r * 40 + k4] = u;
        }
        __syncthreads();
        // A frag: lane holds A[m=ln][k=quad*8+j] of this wave's 16-row tile
        bf16x8 af = *(const bf16x8*)&As[(wave * 16 + ln) * 40 + quad * 8];
        const unsigned short* wfp = Wf + (size_t)ks * 8 * 512 + lane * 8;
#pragma unroll
        for (int nt = 0; nt < 8; ++nt) {
            bf16x8 bf = *(const bf16x8*)(wfp + nt * 512);
            acc[nt] = __builtin_amdgcn_mfma_f32_16x16x32_bf16(af, bf, acc[nt], 0, 0, 0);
        }
        __syncthreads();
    }
    // epilogue: C/D layout col=ln, row=quad*4+r (m89-verified)
    int mbase = m0 + wave * 16 + quad * 4;
#pragma unroll
    for (int nt = 0; nt < 8; ++nt) {
#pragma unroll
        for (int r = 0; r < 4; ++r) {
            int m = mbase + r;
            if (m < NN) Cout[(size_t)m * HC + nt * 16 + ln] = acc[nt][r];
        }
    }
}

// ================= per-node attention logits: one wave per node =================
__global__ __launch_bounds__(256) void alpha_kernel(
    const float* __restrict__ h, const float* __restrict__ att_s,
    const float* __restrict__ att_d, float* __restrict__ as_, float* __restrict__ ad_)
{
    int wave = (blockIdx.x * 256 + threadIdx.x) >> 6;
    int lane = threadIdx.x & 63;
    if (wave >= NN) return;
    float h0 = h[(size_t)wave * HC + lane];
    float h1 = h[(size_t)wave * HC + 64 + lane];
    float s0 = h0 * att_s[lane],      s1 = h1 * att_s[64 + lane];
    float d0 = h0 * att_d[lane],      d1 = h1 * att_d[64 + lane];
#pragma unroll
    for (int o = 32; o > 0; o >>= 1) {
        s0 += __shfl_down(s0, o); s1 += __shfl_down(s1, o);
        d0 += __shfl_down(d0, o); d1 += __shfl_down(d1, o);
    }
    if (lane == 0) {
        as_[wave * 2 + 0] = s0; as_[wave * 2 + 1] = s1;
        ad_[wave * 2 + 0] = d0; ad_[wave * 2 + 1] = d1;
    }
}

// ================= fused segment-softmax + aggregate: one wave per dst node =================
__global__ __launch_bounds__(256) void gat_agg_kernel(
    const int* __restrict__ rowp, const int* __restrict__ esrc,
    const float* __restrict__ as_, const float* __restrict__ ad_,
    const float* __restrict__ h, float* __restrict__ out)
{
    int node = (blockIdx.x * 256 + threadIdx.x) >> 6;
    int lane = threadIdx.x & 63;
    if (node >= NN) return;
    int beg = rowp[node], end = rowp[node + 1];
    float ad0 = ad_[node * 2 + 0], ad1 = ad_[node * 2 + 1];

    float m0 = -3.0e38f, m1 = -3.0e38f;
    float l0 = 0.f, l1 = 0.f, a0 = 0.f, a1 = 0.f;

    for (int j0 = beg; j0 < end; j0 += 64) {
        int nj = min(64, end - j0);
        int   sl  = 0;
        float es0 = 0.f, es1 = 0.f;
        if (j0 + lane < end) {
            sl = esrc[j0 + lane];
            float2 t = *(const float2*)&as_[sl * 2];
            es0 = t.x; es1 = t.y;
        }
        for (int j = 0; j < nj; ++j) {
            int   s  = __shfl(sl, j);
            float e0 = __shfl(es0, j) + ad0; e0 = e0 > 0.f ? e0 : NEG_SLOPE * e0;
            float e1 = __shfl(es1, j) + ad1; e1 = e1 > 0.f ? e1 : NEG_SLOPE * e1;
            float h0 = h[(size_t)s * HC + lane];
            float h1 = h[(size_t)s * HC + 64 + lane];
            float nm0 = fmaxf(m0, e0), nm1 = fmaxf(m1, e1);
            float sc0 = __expf(m0 - nm0), sc1 = __expf(m1 - nm1);
            float p0  = __expf(e0 - nm0), p1  = __expf(e1 - nm1);
            l0 = fmaf(l0, sc0, p0);       l1 = fmaf(l1, sc1, p1);
            a0 = fmaf(a0, sc0, p0 * h0);  a1 = fmaf(a1, sc1, p1 * h1);
            m0 = nm0; m1 = nm1;
        }
    }
    out[(size_t)node * HC + lane]      = a0 / l0;
    out[(size_t)node * HC + 64 + lane] = a1 / l1;
}

// ================= BN stats =================
__global__ __launch_bounds__(256) void bn_stats_kernel(
    const float* __restrict__ x, float* __restrict__ stats)
{
    int c = threadIdx.x & 127;
    int half = threadIdx.x >> 7;
    float s = 0.f, sq = 0.f;
    for (int r = blockIdx.x * 2 + half; r < NN; r += gridDim.x * 2) {
        float v = x[(size_t)r * HC + c];
        s += v; sq += v * v;
    }
    __shared__ float ls[256], lq[256];
    ls[threadIdx.x] = s; lq[threadIdx.x] = sq;
    __syncthreads();
    if (half == 0) {
        s += ls[threadIdx.x + 128];
        sq += lq[threadIdx.x + 128];
        atomicAdd(&stats[c], s);
        atomicAdd(&stats[128 + c], sq);
    }
}

__global__ void bn_params_kernel(
    const float* __restrict__ stats, const float* __restrict__ gamma,
    const float* __restrict__ beta, float* __restrict__ sc, float* __restrict__ sh)
{
    int c = threadIdx.x;
    const float inv_n = 1.0f / (float)NN;
    float mu = stats[c] * inv_n;
    float var = stats[128 + c] * inv_n - mu * mu;
    float rs = rsqrtf(var + BN_EPS);
    float s = gamma[c] * rs;
    sc[c] = s;
    sh[c] = beta[c] - mu * s;
}

// ================= pool (batch sorted -> running accumulation, flush on change) =================
__global__ __launch_bounds__(256) void pool_kernel(
    const float* __restrict__ x, const float* __restrict__ sc,
    const float* __restrict__ sh, const int* __restrict__ batch,
    float* __restrict__ pool, float* __restrict__ cnt)
{
    int c = threadIdx.x & 127;
    int half = threadIdx.x >> 7;
    int r0 = blockIdx.x * 512;
    int rend = min(r0 + 512, NN);
    float s = sc[c], b = sh[c];
    int cur = -1; float acc = 0.f, ccount = 0.f;
    for (int r = r0 + half; r < rend; r += 2) {
        int g = batch[r];
        if (g != cur) {
            if (cur >= 0) {
                atomicAdd(&pool[cur * HC + c], acc);
                if (c == 0) atomicAdd(&cnt[cur], ccount);
            }
            cur = g; acc = 0.f; ccount = 0.f;
        }
        float v = x[(size_t)r * HC + c];
        acc += fmaxf(fmaf(s, v, b), 0.f);
        ccount += 1.f;
    }
    if (cur >= 0) {
        atomicAdd(&pool[cur * HC + c], acc);
        if (c == 0) atomicAdd(&cnt[cur], ccount);
    }
}

// ================= final linear: [64,128]@[128,2] + blin =================
__global__ void final_kernel(
    const float* __restrict__ pool, const float* __restrict__ cnt,
    const float* __restrict__ Wlin, const float* __restrict__ blin,
    float* __restrict__ outp)
{
    int t = threadIdx.x;               // 128 threads
    int b = t >> 1, oc = t & 1;
    float inv = 1.f / fmaxf(cnt[b], 1.f);
    float s = blin[oc];
    for (int c = 0; c < HC; ++c)
        s += pool[b * HC + c] * inv * Wlin[c * 2 + oc];
    outp[b * 2 + oc] = s;
}

// ================= workspace layout =================
// floats
static constexpr size_t OFF_H     = 0;                        // [N*HC]
static constexpr size_t OFF_OUT   = OFF_H   + (size_t)NN*HC;  // [N*HC]
static constexpr size_t OFF_AS    = OFF_OUT + (size_t)NN*HC;  // [N*2]
static constexpr size_t OFF_AD    = OFF_AS  + (size_t)NN*HH;
static constexpr size_t OFF_ST1   = OFF_AD  + (size_t)NN*HH;  // zero from here: [256]
static constexpr size_t OFF_ST2   = OFF_ST1 + 256;
static constexpr size_t OFF_SC1   = OFF_ST2 + 256;            // [128]
static constexpr size_t OFF_SH1   = OFF_SC1 + 128;
static constexpr size_t OFF_SC2   = OFF_SH1 + 128;
static constexpr size_t OFF_SH2   = OFF_SC2 + 128;
static constexpr size_t OFF_POOL  = OFF_SH2 + 128;            // [B*HC]
static constexpr size_t OFF_CNT   = OFF_POOL+ (size_t)BB*HC;  // [B]
static constexpr size_t OFF_ZEND  = OFF_CNT + BB;             // end of zeroed float region
// ints (after float region)
static constexpr size_t IOFF_DEG  = 0;                        // [N]  (zeroed)
static constexpr size_t IOFF_ROWP = IOFF_DEG  + NN;           // [N+1]
static constexpr size_t IOFF_CUR  = IOFF_ROWP + NN + 1;       // [N]
static constexpr size_t IOFF_ESRC = IOFF_CUR  + NN;           // [ETOT]
static constexpr size_t IOFF_WF1  = (IOFF_ESRC + ETOT + 3) & ~(size_t)3;  // 16B-aligned; [512*64] ints (128KB)
static constexpr size_t IOFF_WF2  = IOFF_WF1 + (size_t)IN_C*64;           // [128*64] ints (32KB)
static constexpr size_t IOFF_END  = IOFF_WF2 + (size_t)HC*64;

extern "C" void kernel_launch(void* const* d_in, const int* in_sizes, int n_in,
                              void* d_out, int out_size, void* d_ws, size_t ws_size,
                              hipStream_t stream)
{
    const float* x       = (const float*)d_in[0];
    const int*   ei      = (const int*)  d_in[1];
    const int*   batch   = (const int*)  d_in[2];
    const float* W1      = (const float*)d_in[3];
    const float* atts1   = (const float*)d_in[4];
    const float* attd1   = (const float*)d_in[5];
    const float* gamma1  = (const float*)d_in[7];
    const float* beta1   = (const float*)d_in[8];
    const float* W2      = (const float*)d_in[9];
    const float* atts2   = (const float*)d_in[10];
    const float* attd2   = (const float*)d_in[11];
    const float* gamma2  = (const float*)d_in[13];
    const float* beta2   = (const float*)d_in[14];
    const float* Wlin    = (const float*)d_in[15];
    const float* blin    = (const float*)d_in[16];
    float* outp = (float*)d_out;

    float* ws    = (float*)d_ws;
    float* h     = ws + OFF_H;
    float* out   = ws + OFF_OUT;
    float* as_   = ws + OFF_AS;
    float* ad_   = ws + OFF_AD;
    float* st1   = ws + OFF_ST1;
    float* st2   = ws + OFF_ST2;
    float* sc1   = ws + OFF_SC1;
    float* sh1   = ws + OFF_SH1;
    float* sc2   = ws + OFF_SC2;
    float* sh2   = ws + OFF_SH2;
    float* pool  = ws + OFF_POOL;
    float* cnt   = ws + OFF_CNT;

    int* iws  = (int*)(ws + OFF_ZEND);
    int* deg  = iws + IOFF_DEG;
    int* rowp = iws + IOFF_ROWP;
    int* curp = iws + IOFF_CUR;
    int* esrc = iws + IOFF_ESRC;
    unsigned short* Wf1 = (unsigned short*)(iws + IOFF_WF1);
    unsigned short* Wf2 = (unsigned short*)(iws + IOFF_WF2);

    const int EDGE_BLK  = (ETOT + 255) / 256;
    const int GEMM_BLK  = (NN + 63) / 64;        // 782
    const int WAVE_BLK  = (NN + 3) / 4;          // 1 wave per node, 4 waves/block
    const int POOL_BLK  = (NN + 511) / 512;

    // zero: bn-stats/pool/cnt float region + deg
    hipMemsetAsync(st1, 0, (OFF_ZEND - OFF_ST1) * sizeof(float), stream);
    hipMemsetAsync(deg, 0, NN * sizeof(int), stream);

    // ----- weight fragment packs + CSR build (shared by both layers) -----
    wfrag_kernel<<<(IN_C * 16 + 255) / 256, 256, 0, stream>>>(W1, Wf1, IN_C);
    wfrag_kernel<<<(HC   * 16 + 255) / 256, 256, 0, stream>>>(W2, Wf2, HC);
    deg_kernel<<<EDGE_BLK, 256, 0, stream>>>(ei, deg);
    scan_kernel<<<1, SCAN_T, 0, stream>>>(deg, rowp, curp);
    scatter_kernel<<<EDGE_BLK, 256, 0, stream>>>(ei, curp, esrc);

    // ----- layer 1 -----
    mfma_gemm_kernel<false><<<GEMM_BLK, 256, 0, stream>>>(x, Wf1, h, IN_C, nullptr, nullptr);
    alpha_kernel<<<WAVE_BLK, 256, 0, stream>>>(h, atts1, attd1, as_, ad_);
    gat_agg_kernel<<<WAVE_BLK, 256, 0, stream>>>(rowp, esrc, as_, ad_, h, out);
    bn_stats_kernel<<<512, 256, 0, stream>>>(out, st1);
    bn_params_kernel<<<1, 128, 0, stream>>>(st1, gamma1, beta1, sc1, sh1);

    // ----- layer 2 (BN1-affine+ReLU fused into GEMM2 A-load) -----
    mfma_gemm_kernel<true><<<GEMM_BLK, 256, 0, stream>>>(out, Wf2, h, HC, sc1, sh1);
    alpha_kernel<<<WAVE_BLK, 256, 0, stream>>>(h, atts2, attd2, as_, ad_);
    gat_agg_kernel<<<WAVE_BLK, 256, 0, stream>>>(rowp, esrc, as_, ad_, h, out);
    bn_stats_kernel<<<512, 256, 0, stream>>>(out, st2);
    bn_params_kernel<<<1, 128, 0, stream>>>(st2, gamma2, beta2, sc2, sh2);

    // ----- pool + final linear -----
    pool_kernel<<<POOL_BLK, 256, 0, stream>>>(out, sc2, sh2, batch, pool, cnt);
    final_kernel<<<1, 128, 0, stream>>>(pool, cnt, Wlin, blin, outp);
}

// Round 4
// 624.713 us; speedup vs baseline: 2.4570x; 1.1649x over previous
//
#include <hip/hip_runtime.h>
#include <hip/hip_bf16.h>
#include <cstdint>
#include <cstddef>

// Problem constants (match reference)
#define NN      50000
#define IN_C    512
#define EE      800000
#define ETOT    850000      // E + N self-loops
#define HH      2
#define CC      64
#define HC      128
#define BB      64
#define OUTC    2
#define NEG_SLOPE 0.2f
#define BN_EPS  1e-5f

#define NBLK_SCAN ((NN + 255) / 256)   // 196

typedef __bf16 bf16x8 __attribute__((ext_vector_type(8)));
typedef float  f32x4  __attribute__((ext_vector_type(4)));

__device__ __forceinline__ unsigned short f2bf(float f) {
    __bf16 b = (__bf16)f;                      // RNE convert
    return __builtin_bit_cast(unsigned short, b);
}

__device__ __forceinline__ void edge_sd(const int* __restrict__ ei, int e, int& s, int& d) {
    if (e < EE) { s = ei[e]; d = ei[EE + e]; }
    else        { s = e - EE; d = e - EE; }
}

// ================= CSR build (graph fixed; built once per launch, reused by both layers) =================
__global__ __launch_bounds__(256) void deg_kernel(const int* __restrict__ ei, int* __restrict__ deg)
{
    int e = blockIdx.x * 256 + threadIdx.x;
    if (e >= ETOT) return;
    int d = (e < EE) ? ei[EE + e] : (e - EE);
    atomicAdd(&deg[d], 1);
}

// --- hierarchical scan: (A) block sums, (B) scan of block sums, (C) intra-block scan + offset ---
__global__ __launch_bounds__(256) void bsum_kernel(const int* __restrict__ deg, int* __restrict__ bsum)
{
    int i = blockIdx.x * 256 + threadIdx.x;
    int v = (i < NN) ? deg[i] : 0;
    int lane = threadIdx.x & 63, wv = threadIdx.x >> 6;
#pragma unroll
    for (int o = 32; o > 0; o >>= 1) v += __shfl_down(v, o);
    __shared__ int ws[4];
    if (lane == 0) ws[wv] = v;
    __syncthreads();
    if (threadIdx.x == 0) bsum[blockIdx.x] = ws[0] + ws[1] + ws[2] + ws[3];
}

__global__ __launch_bounds__(256) void bscan_kernel(
    const int* __restrict__ bsum, int* __restrict__ bofs, int* __restrict__ rowp)
{
    int t = threadIdx.x;
    int lane = t & 63, wv = t >> 6;
    int v = (t < NBLK_SCAN) ? bsum[t] : 0;
    int x = v;
#pragma unroll
    for (int o = 1; o < 64; o <<= 1) {
        int y = __shfl_up(x, o);
        if (lane >= o) x += y;
    }
    __shared__ int ws[4];
    if (lane == 63) ws[wv] = x;
    __syncthreads();
    int wo = 0;
#pragma unroll
    for (int w = 0; w < 4; ++w) if (w < wv) wo += ws[w];
    if (t < NBLK_SCAN) bofs[t] = x + wo - v;     // exclusive
    if (t == 0) rowp[NN] = ETOT;
}

__global__ __launch_bounds__(256) void bapply_kernel(
    const int* __restrict__ deg, const int* __restrict__ bofs,
    int* __restrict__ rowp, int* __restrict__ cur)
{
    int i = blockIdx.x * 256 + threadIdx.x;
    int v = (i < NN) ? deg[i] : 0;
    int lane = threadIdx.x & 63, wv = threadIdx.x >> 6;
    int x = v;
#pragma unroll
    for (int o = 1; o < 64; o <<= 1) {
        int y = __shfl_up(x, o);
        if (lane >= o) x += y;
    }
    __shared__ int ws[4];
    if (lane == 63) ws[wv] = x;
    __syncthreads();
    int wo = 0;
#pragma unroll
    for (int w = 0; w < 4; ++w) if (w < wv) wo += ws[w];
    if (i < NN) {
        int r = bofs[blockIdx.x] + x + wo - v;   // exclusive global
        rowp[i] = r; cur[i] = r;
    }
}

__global__ __launch_bounds__(256) void scatter_kernel(
    const int* __restrict__ ei, int* __restrict__ cur, int* __restrict__ esrc)
{
    int e = blockIdx.x * 256 + threadIdx.x;
    if (e >= ETOT) return;
    int s, d; edge_sd(ei, e, s, d);
    int pos = atomicAdd(&cur[d], 1);
    esrc[pos] = s;
}

// ================= W -> bf16 MFMA fragment order =================
// frag id = kblk*8 + ntile; lane holds B[k=kblk*32+quad*8+j][n=ntile*16+ln], j=0..7
__global__ __launch_bounds__(256) void wfrag_kernel(
    const float* __restrict__ W, unsigned short* __restrict__ Wf, int K)
{
    int t = blockIdx.x * 256 + threadIdx.x;       // t = frag*64 + lane
    if (t >= K * 16) return;                      // (K/32)*8*64 == K*16
    int lane = t & 63, frag = t >> 6;
    int kblk = frag >> 3, nt = frag & 7;
    int quad = lane >> 4, ln = lane & 15;
    int kbase = kblk * 32 + quad * 8;
    int n = nt * 16 + ln;
    unsigned short u[8];
#pragma unroll
    for (int j = 0; j < 8; ++j)
        u[j] = f2bf(W[(size_t)(kbase + j) * HC + n]);
    ushort4 a; a.x = u[0]; a.y = u[1]; a.z = u[2]; a.w = u[3];
    ushort4 b; b.x = u[4]; b.y = u[5]; b.z = u[6]; b.w = u[7];
    *(ushort4*)(Wf + (size_t)t * 8)     = a;
    *(ushort4*)(Wf + (size_t)t * 8 + 4) = b;
}

// ================= MFMA GEMM: C[N,128] = f(A[N,K]) @ W[K,128] =================
template<bool AFFINE>
__global__ __launch_bounds__(256) void mfma_gemm_kernel(
    const float* __restrict__ A, const unsigned short* __restrict__ Wf,
    float* __restrict__ Cout, int K,
    const float* __restrict__ sc, const float* __restrict__ sh)
{
    __shared__ unsigned short As[64 * 40];
    const int tid  = threadIdx.x;
    const int wave = tid >> 6, lane = tid & 63;
    const int quad = lane >> 4, ln = lane & 15;
    const int m0 = blockIdx.x * 64;

    f32x4 acc[8];
#pragma unroll
    for (int nt = 0; nt < 8; ++nt) acc[nt] = (f32x4){0.f, 0.f, 0.f, 0.f};

    const int nsteps = K >> 5;
    for (int ks = 0; ks < nsteps; ++ks) {
#pragma unroll
        for (int l = 0; l < 2; ++l) {
            int f  = tid + l * 256;               // 0..511
            int r  = f >> 3;                      // 0..63
            int k4 = (f & 7) << 2;                // 0,4,...,28
            int row = m0 + r;
            float4 v = make_float4(0.f, 0.f, 0.f, 0.f);
            if (row < NN) v = *(const float4*)&A[(size_t)row * K + ks * 32 + k4];
            if (AFFINE) {
                int kk = ks * 32 + k4;
                v.x = fmaxf(fmaf(sc[kk+0], v.x, sh[kk+0]), 0.f);
                v.y = fmaxf(fmaf(sc[kk+1], v.y, sh[kk+1]), 0.f);
                v.z = fmaxf(fmaf(sc[kk+2], v.z, sh[kk+2]), 0.f);
                v.w = fmaxf(fmaf(sc[kk+3], v.w, sh[kk+3]), 0.f);
            }
            ushort4 u; u.x = f2bf(v.x); u.y = f2bf(v.y); u.z = f2bf(v.z); u.w = f2bf(v.w);
            *(ushort4*)&As[r * 40 + k4] = u;
        }
        __syncthreads();
        bf16x8 af = *(const bf16x8*)&As[(wave * 16 + ln) * 40 + quad * 8];
        const unsigned short* wfp = Wf + (size_t)ks * 8 * 512 + lane * 8;
#pragma unroll
        for (int nt = 0; nt < 8; ++nt) {
            bf16x8 bf = *(const bf16x8*)(wfp + nt * 512);
            acc[nt] = __builtin_amdgcn_mfma_f32_16x16x32_bf16(af, bf, acc[nt], 0, 0, 0);
        }
        __syncthreads();
    }
    int mbase = m0 + wave * 16 + quad * 4;
#pragma unroll
    for (int nt = 0; nt < 8; ++nt) {
#pragma unroll
        for (int r = 0; r < 4; ++r) {
            int m = mbase + r;
            if (m < NN) Cout[(size_t)m * HC + nt * 16 + ln] = acc[nt][r];
        }
    }
}

// ================= per-node attention logits: one wave per node =================
__global__ __launch_bounds__(256) void alpha_kernel(
    const float* __restrict__ h, const float* __restrict__ att_s,
    const float* __restrict__ att_d, float* __restrict__ as_, float* __restrict__ ad_)
{
    int wave = (blockIdx.x * 256 + threadIdx.x) >> 6;
    int lane = threadIdx.x & 63;
    if (wave >= NN) return;
    float h0 = h[(size_t)wave * HC + lane];
    float h1 = h[(size_t)wave * HC + 64 + lane];
    float s0 = h0 * att_s[lane],      s1 = h1 * att_s[64 + lane];
    float d0 = h0 * att_d[lane],      d1 = h1 * att_d[64 + lane];
#pragma unroll
    for (int o = 32; o > 0; o >>= 1) {
        s0 += __shfl_down(s0, o); s1 += __shfl_down(s1, o);
        d0 += __shfl_down(d0, o); d1 += __shfl_down(d1, o);
    }
    if (lane == 0) {
        as_[wave * 2 + 0] = s0; as_[wave * 2 + 1] = s1;
        ad_[wave * 2 + 0] = d0; ad_[wave * 2 + 1] = d1;
    }
}

// ================= fused segment-softmax + aggregate: one wave per dst node =================
__global__ __launch_bounds__(256) void gat_agg_kernel(
    const int* __restrict__ rowp, const int* __restrict__ esrc,
    const float* __restrict__ as_, const float* __restrict__ ad_,
    const float* __restrict__ h, float* __restrict__ out)
{
    int node = (blockIdx.x * 256 + threadIdx.x) >> 6;
    int lane = threadIdx.x & 63;
    if (node >= NN) return;
    int beg = rowp[node], end = rowp[node + 1];
    float ad0 = ad_[node * 2 + 0], ad1 = ad_[node * 2 + 1];

    float m0 = -3.0e38f, m1 = -3.0e38f;
    float l0 = 0.f, l1 = 0.f, a0 = 0.f, a1 = 0.f;

    for (int j0 = beg; j0 < end; j0 += 64) {
        int nj = min(64, end - j0);
        int   sl  = 0;
        float es0 = 0.f, es1 = 0.f;
        if (j0 + lane < end) {
            sl = esrc[j0 + lane];
            float2 t = *(const float2*)&as_[sl * 2];
            es0 = t.x; es1 = t.y;
        }
        for (int j = 0; j < nj; ++j) {
            int   s  = __shfl(sl, j);
            float e0 = __shfl(es0, j) + ad0; e0 = e0 > 0.f ? e0 : NEG_SLOPE * e0;
            float e1 = __shfl(es1, j) + ad1; e1 = e1 > 0.f ? e1 : NEG_SLOPE * e1;
            float h0 = h[(size_t)s * HC + lane];
            float h1 = h[(size_t)s * HC + 64 + lane];
            float nm0 = fmaxf(m0, e0), nm1 = fmaxf(m1, e1);
            float sc0 = __expf(m0 - nm0), sc1 = __expf(m1 - nm1);
            float p0  = __expf(e0 - nm0), p1  = __expf(e1 - nm1);
            l0 = fmaf(l0, sc0, p0);       l1 = fmaf(l1, sc1, p1);
            a0 = fmaf(a0, sc0, p0 * h0);  a1 = fmaf(a1, sc1, p1 * h1);
            m0 = nm0; m1 = nm1;
        }
    }
    out[(size_t)node * HC + lane]      = a0 / l0;
    out[(size_t)node * HC + 64 + lane] = a1 / l1;
}

// ================= BN stats =================
__global__ __launch_bounds__(256) void bn_stats_kernel(
    const float* __restrict__ x, float* __restrict__ stats)
{
    int c = threadIdx.x & 127;
    int half = threadIdx.x >> 7;
    float s = 0.f, sq = 0.f;
    for (int r = blockIdx.x * 2 + half; r < NN; r += gridDim.x * 2) {
        float v = x[(size_t)r * HC + c];
        s += v; sq += v * v;
    }
    __shared__ float ls[256], lq[256];
    ls[threadIdx.x] = s; lq[threadIdx.x] = sq;
    __syncthreads();
    if (half == 0) {
        s += ls[threadIdx.x + 128];
        sq += lq[threadIdx.x + 128];
        atomicAdd(&stats[c], s);
        atomicAdd(&stats[128 + c], sq);
    }
}

__global__ void bn_params_kernel(
    const float* __restrict__ stats, const float* __restrict__ gamma,
    const float* __restrict__ beta, float* __restrict__ sc, float* __restrict__ sh)
{
    int c = threadIdx.x;
    const float inv_n = 1.0f / (float)NN;
    float mu = stats[c] * inv_n;
    float var = stats[128 + c] * inv_n - mu * mu;
    float rs = rsqrtf(var + BN_EPS);
    float s = gamma[c] * rs;
    sc[c] = s;
    sh[c] = beta[c] - mu * s;
}

// ================= pool (batch sorted -> running accumulation, flush on change) =================
__global__ __launch_bounds__(256) void pool_kernel(
    const float* __restrict__ x, const float* __restrict__ sc,
    const float* __restrict__ sh, const int* __restrict__ batch,
    float* __restrict__ pool, float* __restrict__ cnt)
{
    int c = threadIdx.x & 127;
    int half = threadIdx.x >> 7;
    int r0 = blockIdx.x * 512;
    int rend = min(r0 + 512, NN);
    float s = sc[c], b = sh[c];
    int cur = -1; float acc = 0.f, ccount = 0.f;
    for (int r = r0 + half; r < rend; r += 2) {
        int g = batch[r];
        if (g != cur) {
            if (cur >= 0) {
                atomicAdd(&pool[cur * HC + c], acc);
                if (c == 0) atomicAdd(&cnt[cur], ccount);
            }
            cur = g; acc = 0.f; ccount = 0.f;
        }
        float v = x[(size_t)r * HC + c];
        acc += fmaxf(fmaf(s, v, b), 0.f);
        ccount += 1.f;
    }
    if (cur >= 0) {
        atomicAdd(&pool[cur * HC + c], acc);
        if (c == 0) atomicAdd(&cnt[cur], ccount);
    }
}

// ================= final linear: [64,128]@[128,2] + blin =================
__global__ void final_kernel(
    const float* __restrict__ pool, const float* __restrict__ cnt,
    const float* __restrict__ Wlin, const float* __restrict__ blin,
    float* __restrict__ outp)
{
    int t = threadIdx.x;               // 128 threads
    int b = t >> 1, oc = t & 1;
    float inv = 1.f / fmaxf(cnt[b], 1.f);
    float s = blin[oc];
    for (int c = 0; c < HC; ++c)
        s += pool[b * HC + c] * inv * Wlin[c * 2 + oc];
    outp[b * 2 + oc] = s;
}

// ================= workspace layout =================
// floats
static constexpr size_t OFF_H     = 0;                        // [N*HC]
static constexpr size_t OFF_OUT   = OFF_H   + (size_t)NN*HC;  // [N*HC]
static constexpr size_t OFF_AS    = OFF_OUT + (size_t)NN*HC;  // [N*2]
static constexpr size_t OFF_AD    = OFF_AS  + (size_t)NN*HH;
static constexpr size_t OFF_ST1   = OFF_AD  + (size_t)NN*HH;  // zero from here: [256]
static constexpr size_t OFF_ST2   = OFF_ST1 + 256;
static constexpr size_t OFF_SC1   = OFF_ST2 + 256;            // [128]
static constexpr size_t OFF_SH1   = OFF_SC1 + 128;
static constexpr size_t OFF_SC2   = OFF_SH1 + 128;
static constexpr size_t OFF_SH2   = OFF_SC2 + 128;
static constexpr size_t OFF_POOL  = OFF_SH2 + 128;            // [B*HC]
static constexpr size_t OFF_CNT   = OFF_POOL+ (size_t)BB*HC;  // [B]
static constexpr size_t OFF_ZEND  = OFF_CNT + BB;             // end of zeroed float region
// ints (after float region)
static constexpr size_t IOFF_DEG  = 0;                        // [N]  (zeroed)
static constexpr size_t IOFF_ROWP = IOFF_DEG  + NN;           // [N+1]
static constexpr size_t IOFF_CUR  = IOFF_ROWP + NN + 1;       // [N]
static constexpr size_t IOFF_BSUM = IOFF_CUR  + NN;           // [NBLK_SCAN]
static constexpr size_t IOFF_BOFS = IOFF_BSUM + NBLK_SCAN;    // [NBLK_SCAN]
static constexpr size_t IOFF_ESRC = IOFF_BOFS + NBLK_SCAN;    // [ETOT]
static constexpr size_t IOFF_WF1  = (IOFF_ESRC + ETOT + 3) & ~(size_t)3;  // 16B-aligned; [512*64] ints
static constexpr size_t IOFF_WF2  = IOFF_WF1 + (size_t)IN_C*64;           // [128*64] ints
static constexpr size_t IOFF_END  = IOFF_WF2 + (size_t)HC*64;

extern "C" void kernel_launch(void* const* d_in, const int* in_sizes, int n_in,
                              void* d_out, int out_size, void* d_ws, size_t ws_size,
                              hipStream_t stream)
{
    const float* x       = (const float*)d_in[0];
    const int*   ei      = (const int*)  d_in[1];
    const int*   batch   = (const int*)  d_in[2];
    const float* W1      = (const float*)d_in[3];
    const float* atts1   = (const float*)d_in[4];
    const float* attd1   = (const float*)d_in[5];
    const float* gamma1  = (const float*)d_in[7];
    const float* beta1   = (const float*)d_in[8];
    const float* W2      = (const float*)d_in[9];
    const float* atts2   = (const float*)d_in[10];
    const float* attd2   = (const float*)d_in[11];
    const float* gamma2  = (const float*)d_in[13];
    const float* beta2   = (const float*)d_in[14];
    const float* Wlin    = (const float*)d_in[15];
    const float* blin    = (const float*)d_in[16];
    float* outp = (float*)d_out;

    float* ws    = (float*)d_ws;
    float* h     = ws + OFF_H;
    float* out   = ws + OFF_OUT;
    float* as_   = ws + OFF_AS;
    float* ad_   = ws + OFF_AD;
    float* st1   = ws + OFF_ST1;
    float* st2   = ws + OFF_ST2;
    float* sc1   = ws + OFF_SC1;
    float* sh1   = ws + OFF_SH1;
    float* sc2   = ws + OFF_SC2;
    float* sh2   = ws + OFF_SH2;
    float* pool  = ws + OFF_POOL;
    float* cnt   = ws + OFF_CNT;

    int* iws  = (int*)(ws + OFF_ZEND);
    int* deg  = iws + IOFF_DEG;
    int* rowp = iws + IOFF_ROWP;
    int* curp = iws + IOFF_CUR;
    int* bsum = iws + IOFF_BSUM;
    int* bofs = iws + IOFF_BOFS;
    int* esrc = iws + IOFF_ESRC;
    unsigned short* Wf1 = (unsigned short*)(iws + IOFF_WF1);
    unsigned short* Wf2 = (unsigned short*)(iws + IOFF_WF2);

    const int EDGE_BLK  = (ETOT + 255) / 256;
    const int GEMM_BLK  = (NN + 63) / 64;        // 782
    const int WAVE_BLK  = (NN + 3) / 4;          // 1 wave per node, 4 waves/block
    const int POOL_BLK  = (NN + 511) / 512;

    // zero: bn-stats/pool/cnt float region + deg
    hipMemsetAsync(st1, 0, (OFF_ZEND - OFF_ST1) * sizeof(float), stream);
    hipMemsetAsync(deg, 0, NN * sizeof(int), stream);

    // ----- weight fragment packs + CSR build (shared by both layers) -----
    wfrag_kernel<<<(IN_C * 16 + 255) / 256, 256, 0, stream>>>(W1, Wf1, IN_C);
    wfrag_kernel<<<(HC   * 16 + 255) / 256, 256, 0, stream>>>(W2, Wf2, HC);
    deg_kernel<<<EDGE_BLK, 256, 0, stream>>>(ei, deg);
    bsum_kernel<<<NBLK_SCAN, 256, 0, stream>>>(deg, bsum);
    bscan_kernel<<<1, 256, 0, stream>>>(bsum, bofs, rowp);
    bapply_kernel<<<NBLK_SCAN, 256, 0, stream>>>(deg, bofs, rowp, curp);
    scatter_kernel<<<EDGE_BLK, 256, 0, stream>>>(ei, curp, esrc);

    // ----- layer 1 -----
    mfma_gemm_kernel<false><<<GEMM_BLK, 256, 0, stream>>>(x, Wf1, h, IN_C, nullptr, nullptr);
    alpha_kernel<<<WAVE_BLK, 256, 0, stream>>>(h, atts1, attd1, as_, ad_);
    gat_agg_kernel<<<WAVE_BLK, 256, 0, stream>>>(rowp, esrc, as_, ad_, h, out);
    bn_stats_kernel<<<512, 256, 0, stream>>>(out, st1);
    bn_params_kernel<<<1, 128, 0, stream>>>(st1, gamma1, beta1, sc1, sh1);

    // ----- layer 2 (BN1-affine+ReLU fused into GEMM2 A-load) -----
    mfma_gemm_kernel<true><<<GEMM_BLK, 256, 0, stream>>>(out, Wf2, h, HC, sc1, sh1);
    alpha_kernel<<<WAVE_BLK, 256, 0, stream>>>(h, atts2, attd2, as_, ad_);
    gat_agg_kernel<<<WAVE_BLK, 256, 0, stream>>>(rowp, esrc, as_, ad_, h, out);
    bn_stats_kernel<<<512, 256, 0, stream>>>(out, st2);
    bn_params_kernel<<<1, 128, 0, stream>>>(st2, gamma2, beta2, sc2, sh2);

    // ----- pool + final linear -----
    pool_kernel<<<POOL_BLK, 256, 0, stream>>>(out, sc2, sh2, batch, pool, cnt);
    final_kernel<<<1, 128, 0, stream>>>(pool, cnt, Wlin, blin, outp);
}

// Round 5
// 567.214 us; speedup vs baseline: 2.7061x; 1.1014x over previous
//
#include <hip/hip_runtime.h>
#include <hip/hip_bf16.h>
#include <cstdint>
#include <cstddef>

// Problem constants (match reference)
#define NN      50000
#define IN_C    512
#define EE      800000
#define ETOT    850000      // E + N self-loops
#define HH      2
#define CC      64
#define HC      128
#define BB      64
#define OUTC    2
#define NEG_SLOPE 0.2f
#define BN_EPS  1e-5f

#define NBLK_SCAN ((NN + 255) / 256)   // 196

typedef __bf16 bf16x8 __attribute__((ext_vector_type(8)));
typedef float  f32x4  __attribute__((ext_vector_type(4)));

__device__ __forceinline__ unsigned short f2bf(float f) {
    __bf16 b = (__bf16)f;                      // RNE convert
    return __builtin_bit_cast(unsigned short, b);
}

__device__ __forceinline__ void edge_sd(const int* __restrict__ ei, int e, int& s, int& d) {
    if (e < EE) { s = ei[e]; d = ei[EE + e]; }
    else        { s = e - EE; d = e - EE; }
}

// ================= CSR build (graph fixed; built once per launch, reused by both layers) =================
__global__ __launch_bounds__(256) void deg_kernel(const int* __restrict__ ei, int* __restrict__ deg)
{
    int e = blockIdx.x * 256 + threadIdx.x;
    if (e >= ETOT) return;
    int d = (e < EE) ? ei[EE + e] : (e - EE);
    atomicAdd(&deg[d], 1);
}

// --- hierarchical scan ---
__global__ __launch_bounds__(256) void bsum_kernel(const int* __restrict__ deg, int* __restrict__ bsum)
{
    int i = blockIdx.x * 256 + threadIdx.x;
    int v = (i < NN) ? deg[i] : 0;
    int lane = threadIdx.x & 63, wv = threadIdx.x >> 6;
#pragma unroll
    for (int o = 32; o > 0; o >>= 1) v += __shfl_down(v, o);
    __shared__ int ws[4];
    if (lane == 0) ws[wv] = v;
    __syncthreads();
    if (threadIdx.x == 0) bsum[blockIdx.x] = ws[0] + ws[1] + ws[2] + ws[3];
}

__global__ __launch_bounds__(256) void bscan_kernel(
    const int* __restrict__ bsum, int* __restrict__ bofs, int* __restrict__ rowp)
{
    int t = threadIdx.x;
    int lane = t & 63, wv = t >> 6;
    int v = (t < NBLK_SCAN) ? bsum[t] : 0;
    int x = v;
#pragma unroll
    for (int o = 1; o < 64; o <<= 1) {
        int y = __shfl_up(x, o);
        if (lane >= o) x += y;
    }
    __shared__ int ws[4];
    if (lane == 63) ws[wv] = x;
    __syncthreads();
    int wo = 0;
#pragma unroll
    for (int w = 0; w < 4; ++w) if (w < wv) wo += ws[w];
    if (t < NBLK_SCAN) bofs[t] = x + wo - v;     // exclusive
    if (t == 0) rowp[NN] = ETOT;
}

__global__ __launch_bounds__(256) void bapply_kernel(
    const int* __restrict__ deg, const int* __restrict__ bofs,
    int* __restrict__ rowp, int* __restrict__ cur)
{
    int i = blockIdx.x * 256 + threadIdx.x;
    int v = (i < NN) ? deg[i] : 0;
    int lane = threadIdx.x & 63, wv = threadIdx.x >> 6;
    int x = v;
#pragma unroll
    for (int o = 1; o < 64; o <<= 1) {
        int y = __shfl_up(x, o);
        if (lane >= o) x += y;
    }
    __shared__ int ws[4];
    if (lane == 63) ws[wv] = x;
    __syncthreads();
    int wo = 0;
#pragma unroll
    for (int w = 0; w < 4; ++w) if (w < wv) wo += ws[w];
    if (i < NN) {
        int r = bofs[blockIdx.x] + x + wo - v;   // exclusive global
        rowp[i] = r; cur[i] = r;
    }
}

__global__ __launch_bounds__(256) void scatter_kernel(
    const int* __restrict__ ei, int* __restrict__ cur, int* __restrict__ esrc)
{
    int e = blockIdx.x * 256 + threadIdx.x;
    if (e >= ETOT) return;
    int s, d; edge_sd(ei, e, s, d);
    int pos = atomicAdd(&cur[d], 1);
    esrc[pos] = s;
}

// ================= W -> bf16 MFMA fragment order =================
__global__ __launch_bounds__(256) void wfrag_kernel(
    const float* __restrict__ W, unsigned short* __restrict__ Wf, int K)
{
    int t = blockIdx.x * 256 + threadIdx.x;       // t = frag*64 + lane
    if (t >= K * 16) return;                      // (K/32)*8*64 == K*16
    int lane = t & 63, frag = t >> 6;
    int kblk = frag >> 3, nt = frag & 7;
    int quad = lane >> 4, ln = lane & 15;
    int kbase = kblk * 32 + quad * 8;
    int n = nt * 16 + ln;
    unsigned short u[8];
#pragma unroll
    for (int j = 0; j < 8; ++j)
        u[j] = f2bf(W[(size_t)(kbase + j) * HC + n]);
    ushort4 a; a.x = u[0]; a.y = u[1]; a.z = u[2]; a.w = u[3];
    ushort4 b; b.x = u[4]; b.y = u[5]; b.z = u[6]; b.w = u[7];
    *(ushort4*)(Wf + (size_t)t * 8)     = a;
    *(ushort4*)(Wf + (size_t)t * 8 + 4) = b;
}

// ================= MFMA GEMM: C[N,128] = f(A[N,K]) @ W[K,128] =================
template<bool AFFINE>
__global__ __launch_bounds__(256) void mfma_gemm_kernel(
    const float* __restrict__ A, const unsigned short* __restrict__ Wf,
    float* __restrict__ Cout, int K,
    const float* __restrict__ sc, const float* __restrict__ sh)
{
    __shared__ unsigned short As[64 * 40];
    const int tid  = threadIdx.x;
    const int wave = tid >> 6, lane = tid & 63;
    const int quad = lane >> 4, ln = lane & 15;
    const int m0 = blockIdx.x * 64;

    f32x4 acc[8];
#pragma unroll
    for (int nt = 0; nt < 8; ++nt) acc[nt] = (f32x4){0.f, 0.f, 0.f, 0.f};

    const int nsteps = K >> 5;
    for (int ks = 0; ks < nsteps; ++ks) {
#pragma unroll
        for (int l = 0; l < 2; ++l) {
            int f  = tid + l * 256;               // 0..511
            int r  = f >> 3;                      // 0..63
            int k4 = (f & 7) << 2;                // 0,4,...,28
            int row = m0 + r;
            float4 v = make_float4(0.f, 0.f, 0.f, 0.f);
            if (row < NN) v = *(const float4*)&A[(size_t)row * K + ks * 32 + k4];
            if (AFFINE) {
                int kk = ks * 32 + k4;
                v.x = fmaxf(fmaf(sc[kk+0], v.x, sh[kk+0]), 0.f);
                v.y = fmaxf(fmaf(sc[kk+1], v.y, sh[kk+1]), 0.f);
                v.z = fmaxf(fmaf(sc[kk+2], v.z, sh[kk+2]), 0.f);
                v.w = fmaxf(fmaf(sc[kk+3], v.w, sh[kk+3]), 0.f);
            }
            ushort4 u; u.x = f2bf(v.x); u.y = f2bf(v.y); u.z = f2bf(v.z); u.w = f2bf(v.w);
            *(ushort4*)&As[r * 40 + k4] = u;
        }
        __syncthreads();
        bf16x8 af = *(const bf16x8*)&As[(wave * 16 + ln) * 40 + quad * 8];
        const unsigned short* wfp = Wf + (size_t)ks * 8 * 512 + lane * 8;
#pragma unroll
        for (int nt = 0; nt < 8; ++nt) {
            bf16x8 bf = *(const bf16x8*)(wfp + nt * 512);
            acc[nt] = __builtin_amdgcn_mfma_f32_16x16x32_bf16(af, bf, acc[nt], 0, 0, 0);
        }
        __syncthreads();
    }
    int mbase = m0 + wave * 16 + quad * 4;
#pragma unroll
    for (int nt = 0; nt < 8; ++nt) {
#pragma unroll
        for (int r = 0; r < 4; ++r) {
            int m = mbase + r;
            if (m < NN) Cout[(size_t)m * HC + nt * 16 + ln] = acc[nt][r];
        }
    }
}

// ================= per-node attention logits: one wave per node =================
__global__ __launch_bounds__(256) void alpha_kernel(
    const float* __restrict__ h, const float* __restrict__ att_s,
    const float* __restrict__ att_d, float* __restrict__ as_, float* __restrict__ ad_)
{
    int wave = (blockIdx.x * 256 + threadIdx.x) >> 6;
    int lane = threadIdx.x & 63;
    if (wave >= NN) return;
    float h0 = h[(size_t)wave * HC + lane];
    float h1 = h[(size_t)wave * HC + 64 + lane];
    float s0 = h0 * att_s[lane],      s1 = h1 * att_s[64 + lane];
    float d0 = h0 * att_d[lane],      d1 = h1 * att_d[64 + lane];
#pragma unroll
    for (int o = 32; o > 0; o >>= 1) {
        s0 += __shfl_down(s0, o); s1 += __shfl_down(s1, o);
        d0 += __shfl_down(d0, o); d1 += __shfl_down(d1, o);
    }
    if (lane == 0) {
        as_[wave * 2 + 0] = s0; as_[wave * 2 + 1] = s1;
        ad_[wave * 2 + 0] = d0; ad_[wave * 2 + 1] = d1;
    }
}

// ================= fused segment-softmax + aggregate: one wave per dst node =================
__global__ __launch_bounds__(256) void gat_agg_kernel(
    const int* __restrict__ rowp, const int* __restrict__ esrc,
    const float* __restrict__ as_, const float* __restrict__ ad_,
    const float* __restrict__ h, float* __restrict__ out)
{
    int node = (blockIdx.x * 256 + threadIdx.x) >> 6;
    int lane = threadIdx.x & 63;
    if (node >= NN) return;
    int beg = rowp[node], end = rowp[node + 1];
    float ad0 = ad_[node * 2 + 0], ad1 = ad_[node * 2 + 1];

    float m0 = -3.0e38f, m1 = -3.0e38f;
    float l0 = 0.f, l1 = 0.f, a0 = 0.f, a1 = 0.f;

    for (int j0 = beg; j0 < end; j0 += 64) {
        int nj = min(64, end - j0);
        int   sl  = 0;
        float es0 = 0.f, es1 = 0.f;
        if (j0 + lane < end) {
            sl = esrc[j0 + lane];
            float2 t = *(const float2*)&as_[sl * 2];
            es0 = t.x; es1 = t.y;
        }
        for (int j = 0; j < nj; ++j) {
            int   s  = __shfl(sl, j);
            float e0 = __shfl(es0, j) + ad0; e0 = e0 > 0.f ? e0 : NEG_SLOPE * e0;
            float e1 = __shfl(es1, j) + ad1; e1 = e1 > 0.f ? e1 : NEG_SLOPE * e1;
            float h0 = h[(size_t)s * HC + lane];
            float h1 = h[(size_t)s * HC + 64 + lane];
            float nm0 = fmaxf(m0, e0), nm1 = fmaxf(m1, e1);
            float sc0 = __expf(m0 - nm0), sc1 = __expf(m1 - nm1);
            float p0  = __expf(e0 - nm0), p1  = __expf(e1 - nm1);
            l0 = fmaf(l0, sc0, p0);       l1 = fmaf(l1, sc1, p1);
            a0 = fmaf(a0, sc0, p0 * h0);  a1 = fmaf(a1, sc1, p1 * h1);
            m0 = nm0; m1 = nm1;
        }
    }
    out[(size_t)node * HC + lane]      = a0 / l0;
    out[(size_t)node * HC + 64 + lane] = a1 / l1;
}

// ================= BN stats =================
__global__ __launch_bounds__(256) void bn_stats_kernel(
    const float* __restrict__ x, float* __restrict__ stats)
{
    int c = threadIdx.x & 127;
    int half = threadIdx.x >> 7;
    float s = 0.f, sq = 0.f;
    for (int r = blockIdx.x * 2 + half; r < NN; r += gridDim.x * 2) {
        float v = x[(size_t)r * HC + c];
        s += v; sq += v * v;
    }
    __shared__ float ls[256], lq[256];
    ls[threadIdx.x] = s; lq[threadIdx.x] = sq;
    __syncthreads();
    if (half == 0) {
        s += ls[threadIdx.x + 128];
        sq += lq[threadIdx.x + 128];
        atomicAdd(&stats[c], s);
        atomicAdd(&stats[128 + c], sq);
    }
}

__global__ void bn_params_kernel(
    const float* __restrict__ stats, const float* __restrict__ gamma,
    const float* __restrict__ beta, float* __restrict__ sc, float* __restrict__ sh)
{
    int c = threadIdx.x;
    const float inv_n = 1.0f / (float)NN;
    float mu = stats[c] * inv_n;
    float var = stats[128 + c] * inv_n - mu * mu;
    float rs = rsqrtf(var + BN_EPS);
    float s = gamma[c] * rs;
    sc[c] = s;
    sh[c] = beta[c] - mu * s;
}

// ================= pool: 64 rows/block (782 blocks), flush-on-graph-change =================
__global__ __launch_bounds__(256) void pool_kernel(
    const float* __restrict__ x, const float* __restrict__ sc,
    const float* __restrict__ sh, const int* __restrict__ batch,
    float* __restrict__ pool, float* __restrict__ cnt)
{
    int c = threadIdx.x & 127;
    int half = threadIdx.x >> 7;
    int r0 = blockIdx.x * 64;
    int rend = min(r0 + 64, NN);
    float s = sc[c], b = sh[c];
    int cur = -1; float acc = 0.f, ccount = 0.f;
    for (int r = r0 + half; r < rend; r += 2) {
        int g = batch[r];
        if (g != cur) {
            if (cur >= 0) {
                atomicAdd(&pool[cur * HC + c], acc);
                if (c == 0) atomicAdd(&cnt[cur], ccount);
            }
            cur = g; acc = 0.f; ccount = 0.f;
        }
        float v = x[(size_t)r * HC + c];
        acc += fmaxf(fmaf(s, v, b), 0.f);
        ccount += 1.f;
    }
    if (cur >= 0) {
        atomicAdd(&pool[cur * HC + c], acc);
        if (c == 0) atomicAdd(&cnt[cur], ccount);
    }
}

// ================= final linear: [64,128]@[128,2] + blin =================
__global__ void final_kernel(
    const float* __restrict__ pool, const float* __restrict__ cnt,
    const float* __restrict__ Wlin, const float* __restrict__ blin,
    float* __restrict__ outp)
{
    int t = threadIdx.x;               // 128 threads
    int b = t >> 1, oc = t & 1;
    float inv = 1.f / fmaxf(cnt[b], 1.f);
    float s = blin[oc];
    for (int c = 0; c < HC; ++c)
        s += pool[b * HC + c] * inv * Wlin[c * 2 + oc];
    outp[b * 2 + oc] = s;
}

// ================= workspace layout =================
// floats
static constexpr size_t OFF_H     = 0;                        // [N*HC]
static constexpr size_t OFF_OUT   = OFF_H   + (size_t)NN*HC;  // [N*HC]
static constexpr size_t OFF_AS    = OFF_OUT + (size_t)NN*HC;  // [N*2]
static constexpr size_t OFF_AD    = OFF_AS  + (size_t)NN*HH;
static constexpr size_t OFF_ST1   = OFF_AD  + (size_t)NN*HH;  // zero from here: [256]
static constexpr size_t OFF_ST2   = OFF_ST1 + 256;
static constexpr size_t OFF_SC1   = OFF_ST2 + 256;            // [128]
static constexpr size_t OFF_SH1   = OFF_SC1 + 128;
static constexpr size_t OFF_SC2   = OFF_SH1 + 128;
static constexpr size_t OFF_SH2   = OFF_SC2 + 128;
static constexpr size_t OFF_POOL  = OFF_SH2 + 128;            // [B*HC]
static constexpr size_t OFF_CNT   = OFF_POOL+ (size_t)BB*HC;  // [B]
static constexpr size_t OFF_ZEND  = OFF_CNT + BB;             // end of zeroed float region
// ints (after float region)
static constexpr size_t IOFF_DEG  = 0;                        // [N]  (zeroed)
static constexpr size_t IOFF_ROWP = IOFF_DEG  + NN;           // [N+1]
static constexpr size_t IOFF_CUR  = IOFF_ROWP + NN + 1;       // [N]
static constexpr size_t IOFF_BSUM = IOFF_CUR  + NN;           // [NBLK_SCAN]
static constexpr size_t IOFF_BOFS = IOFF_BSUM + NBLK_SCAN;    // [NBLK_SCAN]
static constexpr size_t IOFF_ESRC = IOFF_BOFS + NBLK_SCAN;    // [ETOT]
static constexpr size_t IOFF_WF1  = (IOFF_ESRC + ETOT + 3) & ~(size_t)3;  // 16B-aligned; [512*64] ints
static constexpr size_t IOFF_WF2  = IOFF_WF1 + (size_t)IN_C*64;           // [128*64] ints
static constexpr size_t IOFF_END  = IOFF_WF2 + (size_t)HC*64;

extern "C" void kernel_launch(void* const* d_in, const int* in_sizes, int n_in,
                              void* d_out, int out_size, void* d_ws, size_t ws_size,
                              hipStream_t stream)
{
    const float* x       = (const float*)d_in[0];
    const int*   ei      = (const int*)  d_in[1];
    const int*   batch   = (const int*)  d_in[2];
    const float* W1      = (const float*)d_in[3];
    const float* atts1   = (const float*)d_in[4];
    const float* attd1   = (const float*)d_in[5];
    const float* gamma1  = (const float*)d_in[7];
    const float* beta1   = (const float*)d_in[8];
    const float* W2      = (const float*)d_in[9];
    const float* atts2   = (const float*)d_in[10];
    const float* attd2   = (const float*)d_in[11];
    const float* gamma2  = (const float*)d_in[13];
    const float* beta2   = (const float*)d_in[14];
    const float* Wlin    = (const float*)d_in[15];
    const float* blin    = (const float*)d_in[16];
    float* outp = (float*)d_out;

    float* ws    = (float*)d_ws;
    float* h     = ws + OFF_H;
    float* out   = ws + OFF_OUT;
    float* as_   = ws + OFF_AS;
    float* ad_   = ws + OFF_AD;
    float* st1   = ws + OFF_ST1;
    float* st2   = ws + OFF_ST2;
    float* sc1   = ws + OFF_SC1;
    float* sh1   = ws + OFF_SH1;
    float* sc2   = ws + OFF_SC2;
    float* sh2   = ws + OFF_SH2;
    float* pool  = ws + OFF_POOL;
    float* cnt   = ws + OFF_CNT;

    int* iws  = (int*)(ws + OFF_ZEND);
    int* deg  = iws + IOFF_DEG;
    int* rowp = iws + IOFF_ROWP;
    int* curp = iws + IOFF_CUR;
    int* bsum = iws + IOFF_BSUM;
    int* bofs = iws + IOFF_BOFS;
    int* esrc = iws + IOFF_ESRC;
    unsigned short* Wf1 = (unsigned short*)(iws + IOFF_WF1);
    unsigned short* Wf2 = (unsigned short*)(iws + IOFF_WF2);

    const int EDGE_BLK  = (ETOT + 255) / 256;
    const int GEMM_BLK  = (NN + 63) / 64;        // 782
    const int WAVE_BLK  = (NN + 3) / 4;          // 1 wave per node, 4 waves/block
    const int POOL_BLK  = (NN + 63) / 64;        // 782: 64 rows/block

    // zero: bn-stats/pool/cnt float region + deg
    hipMemsetAsync(st1, 0, (OFF_ZEND - OFF_ST1) * sizeof(float), stream);
    hipMemsetAsync(deg, 0, NN * sizeof(int), stream);

    // ----- weight fragment packs + CSR build (shared by both layers) -----
    wfrag_kernel<<<(IN_C * 16 + 255) / 256, 256, 0, stream>>>(W1, Wf1, IN_C);
    wfrag_kernel<<<(HC   * 16 + 255) / 256, 256, 0, stream>>>(W2, Wf2, HC);
    deg_kernel<<<EDGE_BLK, 256, 0, stream>>>(ei, deg);
    bsum_kernel<<<NBLK_SCAN, 256, 0, stream>>>(deg, bsum);
    bscan_kernel<<<1, 256, 0, stream>>>(bsum, bofs, rowp);
    bapply_kernel<<<NBLK_SCAN, 256, 0, stream>>>(deg, bofs, rowp, curp);
    scatter_kernel<<<EDGE_BLK, 256, 0, stream>>>(ei, curp, esrc);

    // ----- layer 1 -----
    mfma_gemm_kernel<false><<<GEMM_BLK, 256, 0, stream>>>(x, Wf1, h, IN_C, nullptr, nullptr);
    alpha_kernel<<<WAVE_BLK, 256, 0, stream>>>(h, atts1, attd1, as_, ad_);
    gat_agg_kernel<<<WAVE_BLK, 256, 0, stream>>>(rowp, esrc, as_, ad_, h, out);
    bn_stats_kernel<<<512, 256, 0, stream>>>(out, st1);
    bn_params_kernel<<<1, 128, 0, stream>>>(st1, gamma1, beta1, sc1, sh1);

    // ----- layer 2 (BN1-affine+ReLU fused into GEMM2 A-load) -----
    mfma_gemm_kernel<true><<<GEMM_BLK, 256, 0, stream>>>(out, Wf2, h, HC, sc1, sh1);
    alpha_kernel<<<WAVE_BLK, 256, 0, stream>>>(h, atts2, attd2, as_, ad_);
    gat_agg_kernel<<<WAVE_BLK, 256, 0, stream>>>(rowp, esrc, as_, ad_, h, out);
    bn_stats_kernel<<<512, 256, 0, stream>>>(out, st2);
    bn_params_kernel<<<1, 128, 0, stream>>>(st2, gamma2, beta2, sc2, sh2);

    // ----- pool + final linear -----
    pool_kernel<<<POOL_BLK, 256, 0, stream>>>(out, sc2, sh2, batch, pool, cnt);
    final_kernel<<<1, 128, 0, stream>>>(pool, cnt, Wlin, blin, outp);
}

// Round 6
// 529.049 us; speedup vs baseline: 2.9013x; 1.0721x over previous
//
#include <hip/hip_runtime.h>
#include <hip/hip_bf16.h>
#include <cstdint>
#include <cstddef>

// Problem constants (match reference)
#define NN      50000
#define IN_C    512
#define EE      800000
#define ETOT    850000      // E + N self-loops
#define HH      2
#define CC      64
#define HC      128
#define BB      64
#define OUTC    2
#define NEG_SLOPE 0.2f
#define BN_EPS  1e-5f

#define NBLK_SCAN ((NN + 255) / 256)   // 196

typedef __bf16 bf16x8 __attribute__((ext_vector_type(8)));
typedef float  f32x4  __attribute__((ext_vector_type(4)));

__device__ __forceinline__ unsigned f2bf(float f) {
    __bf16 b = (__bf16)f;                      // RNE convert
    return (unsigned)__builtin_bit_cast(unsigned short, b);
}

__device__ __forceinline__ void edge_sd(const int* __restrict__ ei, int e, int& s, int& d) {
    if (e < EE) { s = ei[e]; d = ei[EE + e]; }
    else        { s = e - EE; d = e - EE; }
}

// ================= CSR build (graph fixed; built once per launch, reused by both layers) =================
__global__ __launch_bounds__(256) void deg_kernel(const int* __restrict__ ei, int* __restrict__ deg)
{
    int e = blockIdx.x * 256 + threadIdx.x;
    if (e >= ETOT) return;
    int d = (e < EE) ? ei[EE + e] : (e - EE);
    atomicAdd(&deg[d], 1);
}

// --- hierarchical scan ---
__global__ __launch_bounds__(256) void bsum_kernel(const int* __restrict__ deg, int* __restrict__ bsum)
{
    int i = blockIdx.x * 256 + threadIdx.x;
    int v = (i < NN) ? deg[i] : 0;
    int lane = threadIdx.x & 63, wv = threadIdx.x >> 6;
#pragma unroll
    for (int o = 32; o > 0; o >>= 1) v += __shfl_down(v, o);
    __shared__ int ws[4];
    if (lane == 0) ws[wv] = v;
    __syncthreads();
    if (threadIdx.x == 0) bsum[blockIdx.x] = ws[0] + ws[1] + ws[2] + ws[3];
}

__global__ __launch_bounds__(256) void bscan_kernel(
    const int* __restrict__ bsum, int* __restrict__ bofs, int* __restrict__ rowp)
{
    int t = threadIdx.x;
    int lane = t & 63, wv = t >> 6;
    int v = (t < NBLK_SCAN) ? bsum[t] : 0;
    int x = v;
#pragma unroll
    for (int o = 1; o < 64; o <<= 1) {
        int y = __shfl_up(x, o);
        if (lane >= o) x += y;
    }
    __shared__ int ws[4];
    if (lane == 63) ws[wv] = x;
    __syncthreads();
    int wo = 0;
#pragma unroll
    for (int w = 0; w < 4; ++w) if (w < wv) wo += ws[w];
    if (t < NBLK_SCAN) bofs[t] = x + wo - v;     // exclusive
    if (t == 0) rowp[NN] = ETOT;
}

__global__ __launch_bounds__(256) void bapply_kernel(
    const int* __restrict__ deg, const int* __restrict__ bofs,
    int* __restrict__ rowp, int* __restrict__ cur)
{
    int i = blockIdx.x * 256 + threadIdx.x;
    int v = (i < NN) ? deg[i] : 0;
    int lane = threadIdx.x & 63, wv = threadIdx.x >> 6;
    int x = v;
#pragma unroll
    for (int o = 1; o < 64; o <<= 1) {
        int y = __shfl_up(x, o);
        if (lane >= o) x += y;
    }
    __shared__ int ws[4];
    if (lane == 63) ws[wv] = x;
    __syncthreads();
    int wo = 0;
#pragma unroll
    for (int w = 0; w < 4; ++w) if (w < wv) wo += ws[w];
    if (i < NN) {
        int r = bofs[blockIdx.x] + x + wo - v;   // exclusive global
        rowp[i] = r; cur[i] = r;
    }
}

__global__ __launch_bounds__(256) void scatter_kernel(
    const int* __restrict__ ei, int* __restrict__ cur, int* __restrict__ esrc)
{
    int e = blockIdx.x * 256 + threadIdx.x;
    if (e >= ETOT) return;
    int s, d; edge_sd(ei, e, s, d);
    int pos = atomicAdd(&cur[d], 1);
    esrc[pos] = s;
}

// ================= W -> bf16 MFMA fragment order =================
__global__ __launch_bounds__(256) void wfrag_kernel(
    const float* __restrict__ W, unsigned short* __restrict__ Wf, int K)
{
    int t = blockIdx.x * 256 + threadIdx.x;       // t = frag*64 + lane
    if (t >= K * 16) return;                      // (K/32)*8*64 == K*16
    int lane = t & 63, frag = t >> 6;
    int kblk = frag >> 3, nt = frag & 7;
    int quad = lane >> 4, ln = lane & 15;
    int kbase = kblk * 32 + quad * 8;
    int n = nt * 16 + ln;
    unsigned short u[8];
#pragma unroll
    for (int j = 0; j < 8; ++j)
        u[j] = (unsigned short)f2bf(W[(size_t)(kbase + j) * HC + n]);
    ushort4 a; a.x = u[0]; a.y = u[1]; a.z = u[2]; a.w = u[3];
    ushort4 b; b.x = u[4]; b.y = u[5]; b.z = u[6]; b.w = u[7];
    *(ushort4*)(Wf + (size_t)t * 8)     = a;
    *(ushort4*)(Wf + (size_t)t * 8 + 4) = b;
}

// ================= MFMA GEMM + fused alpha + bf16 pack =================
// C = f(A[N,K]) @ W[K,128]. Outputs: hb (bf16 pair-packed h), as_/ad_ (attention logits).
// No fp32 C write (nothing downstream needs it).
template<bool AFFINE>
__global__ __launch_bounds__(256) void mfma_gemm_kernel(
    const float* __restrict__ A, const unsigned short* __restrict__ Wf,
    const float* __restrict__ atts, const float* __restrict__ attd,
    unsigned* __restrict__ hb, float* __restrict__ as_, float* __restrict__ ad_,
    int K, const float* __restrict__ sc, const float* __restrict__ sh)
{
    __shared__ unsigned short As[64 * 40];
    const int tid  = threadIdx.x;
    const int wave = tid >> 6, lane = tid & 63;
    const int quad = lane >> 4, ln = lane & 15;
    const int m0 = blockIdx.x * 64;

    f32x4 acc[8];
#pragma unroll
    for (int nt = 0; nt < 8; ++nt) acc[nt] = (f32x4){0.f, 0.f, 0.f, 0.f};

    const int nsteps = K >> 5;
    for (int ks = 0; ks < nsteps; ++ks) {
#pragma unroll
        for (int l = 0; l < 2; ++l) {
            int f  = tid + l * 256;               // 0..511
            int r  = f >> 3;                      // 0..63
            int k4 = (f & 7) << 2;                // 0,4,...,28
            int row = m0 + r;
            float4 v = make_float4(0.f, 0.f, 0.f, 0.f);
            if (row < NN) v = *(const float4*)&A[(size_t)row * K + ks * 32 + k4];
            if (AFFINE) {
                int kk = ks * 32 + k4;
                v.x = fmaxf(fmaf(sc[kk+0], v.x, sh[kk+0]), 0.f);
                v.y = fmaxf(fmaf(sc[kk+1], v.y, sh[kk+1]), 0.f);
                v.z = fmaxf(fmaf(sc[kk+2], v.z, sh[kk+2]), 0.f);
                v.w = fmaxf(fmaf(sc[kk+3], v.w, sh[kk+3]), 0.f);
            }
            ushort4 u;
            u.x = (unsigned short)f2bf(v.x); u.y = (unsigned short)f2bf(v.y);
            u.z = (unsigned short)f2bf(v.z); u.w = (unsigned short)f2bf(v.w);
            *(ushort4*)&As[r * 40 + k4] = u;
        }
        __syncthreads();
        bf16x8 af = *(const bf16x8*)&As[(wave * 16 + ln) * 40 + quad * 8];
        const unsigned short* wfp = Wf + (size_t)ks * 8 * 512 + lane * 8;
#pragma unroll
        for (int nt = 0; nt < 8; ++nt) {
            bf16x8 bf = *(const bf16x8*)(wfp + nt * 512);
            acc[nt] = __builtin_amdgcn_mfma_f32_16x16x32_bf16(af, bf, acc[nt], 0, 0, 0);
        }
        __syncthreads();
    }
    // epilogue: pack bf16 pairs + fused attention logits; C/D layout col=ln, row=quad*4+r
    const int mbase = m0 + wave * 16 + quad * 4;
#pragma unroll
    for (int r = 0; r < 4; ++r) {
        int m = mbase + r;
        bool ok = (m < NN);
        float ps0 = 0.f, ps1 = 0.f, pd0 = 0.f, pd1 = 0.f;
#pragma unroll
        for (int nt = 0; nt < 8; ++nt) {
            float v  = acc[nt][r];
            float ws = atts[nt * 16 + ln], wd = attd[nt * 16 + ln];
            if (nt < 4) { ps0 = fmaf(v, ws, ps0); pd0 = fmaf(v, wd, pd0); }
            else        { ps1 = fmaf(v, ws, ps1); pd1 = fmaf(v, wd, pd1); }
        }
#pragma unroll
        for (int nt = 0; nt < 4; ++nt) {
            unsigned pk = f2bf(acc[nt][r]) | (f2bf(acc[nt + 4][r]) << 16);
            if (ok) hb[(size_t)m * 64 + nt * 16 + ln] = pk;
        }
#pragma unroll
        for (int o = 8; o > 0; o >>= 1) {
            ps0 += __shfl_down(ps0, o); ps1 += __shfl_down(ps1, o);
            pd0 += __shfl_down(pd0, o); pd1 += __shfl_down(pd1, o);
        }
        if (ok && ln == 0) {
            *(float2*)&as_[m * 2] = make_float2(ps0, ps1);
            *(float2*)&ad_[m * 2] = make_float2(pd0, pd1);
        }
    }
}

// ================= fused segment-softmax + aggregate: one wave per dst node =================
// No max-subtraction (shift-invariant; logits bounded ~|8|, exp safe in fp32).
// lane owns channels (lane, lane+64) via one packed-uint gather from hb.
__global__ __launch_bounds__(256) void gat_agg_kernel(
    const int* __restrict__ rowp, const int* __restrict__ esrc,
    const float* __restrict__ as_, const float* __restrict__ ad_,
    const unsigned* __restrict__ hb, float* __restrict__ out)
{
    int node = (blockIdx.x * 256 + threadIdx.x) >> 6;
    int lane = threadIdx.x & 63;
    if (node >= NN) return;
    int beg = rowp[node], end = rowp[node + 1];
    float ad0 = ad_[node * 2 + 0], ad1 = ad_[node * 2 + 1];

    float l0 = 0.f, l1 = 0.f, a0 = 0.f, a1 = 0.f;

    for (int j0 = beg; j0 < end; j0 += 64) {
        int nj = min(64, end - j0);
        int   sl  = 0;
        float es0 = 0.f, es1 = 0.f;
        if (j0 + lane < end) {
            sl = esrc[j0 + lane];
            float2 t = *(const float2*)&as_[sl * 2];
            es0 = t.x; es1 = t.y;
        }
        for (int j = 0; j < nj; ++j) {
            int   s  = __shfl(sl, j);
            float e0 = __shfl(es0, j) + ad0; e0 = fmaxf(e0, NEG_SLOPE * e0);
            float e1 = __shfl(es1, j) + ad1; e1 = fmaxf(e1, NEG_SLOPE * e1);
            float p0 = __expf(e0), p1 = __expf(e1);
            unsigned u = hb[(size_t)s * 64 + lane];
            float h0 = __uint_as_float(u << 16);
            float h1 = __uint_as_float(u & 0xffff0000u);
            l0 += p0; l1 += p1;
            a0 = fmaf(p0, h0, a0); a1 = fmaf(p1, h1, a1);
        }
    }
    out[(size_t)node * HC + lane]      = a0 / l0;
    out[(size_t)node * HC + 64 + lane] = a1 / l1;
}

// ================= BN stats =================
__global__ __launch_bounds__(256) void bn_stats_kernel(
    const float* __restrict__ x, float* __restrict__ stats)
{
    int c = threadIdx.x & 127;
    int half = threadIdx.x >> 7;
    float s = 0.f, sq = 0.f;
    for (int r = blockIdx.x * 2 + half; r < NN; r += gridDim.x * 2) {
        float v = x[(size_t)r * HC + c];
        s += v; sq += v * v;
    }
    __shared__ float ls[256], lq[256];
    ls[threadIdx.x] = s; lq[threadIdx.x] = sq;
    __syncthreads();
    if (half == 0) {
        s += ls[threadIdx.x + 128];
        sq += lq[threadIdx.x + 128];
        atomicAdd(&stats[c], s);
        atomicAdd(&stats[128 + c], sq);
    }
}

__global__ void bn_params_kernel(
    const float* __restrict__ stats, const float* __restrict__ gamma,
    const float* __restrict__ beta, float* __restrict__ sc, float* __restrict__ sh)
{
    int c = threadIdx.x;
    const float inv_n = 1.0f / (float)NN;
    float mu = stats[c] * inv_n;
    float var = stats[128 + c] * inv_n - mu * mu;
    float rs = rsqrtf(var + BN_EPS);
    float s = gamma[c] * rs;
    sc[c] = s;
    sh[c] = beta[c] - mu * s;
}

// ================= pool: 64 rows/block (782 blocks), flush-on-graph-change =================
__global__ __launch_bounds__(256) void pool_kernel(
    const float* __restrict__ x, const float* __restrict__ sc,
    const float* __restrict__ sh, const int* __restrict__ batch,
    float* __restrict__ pool, float* __restrict__ cnt)
{
    int c = threadIdx.x & 127;
    int half = threadIdx.x >> 7;
    int r0 = blockIdx.x * 64;
    int rend = min(r0 + 64, NN);
    float s = sc[c], b = sh[c];
    int cur = -1; float acc = 0.f, ccount = 0.f;
    for (int r = r0 + half; r < rend; r += 2) {
        int g = batch[r];
        if (g != cur) {
            if (cur >= 0) {
                atomicAdd(&pool[cur * HC + c], acc);
                if (c == 0) atomicAdd(&cnt[cur], ccount);
            }
            cur = g; acc = 0.f; ccount = 0.f;
        }
        float v = x[(size_t)r * HC + c];
        acc += fmaxf(fmaf(s, v, b), 0.f);
        ccount += 1.f;
    }
    if (cur >= 0) {
        atomicAdd(&pool[cur * HC + c], acc);
        if (c == 0) atomicAdd(&cnt[cur], ccount);
    }
}

// ================= final linear: [64,128]@[128,2] + blin =================
__global__ void final_kernel(
    const float* __restrict__ pool, const float* __restrict__ cnt,
    const float* __restrict__ Wlin, const float* __restrict__ blin,
    float* __restrict__ outp)
{
    int t = threadIdx.x;               // 128 threads
    int b = t >> 1, oc = t & 1;
    float inv = 1.f / fmaxf(cnt[b], 1.f);
    float s = blin[oc];
    for (int c = 0; c < HC; ++c)
        s += pool[b * HC + c] * inv * Wlin[c * 2 + oc];
    outp[b * 2 + oc] = s;
}

// ================= workspace layout =================
// floats
static constexpr size_t OFF_OUT   = 0;                        // [N*HC]
static constexpr size_t OFF_AS    = OFF_OUT + (size_t)NN*HC;  // [N*2]
static constexpr size_t OFF_AD    = OFF_AS  + (size_t)NN*HH;
static constexpr size_t OFF_ST1   = OFF_AD  + (size_t)NN*HH;  // zero from here: [256]
static constexpr size_t OFF_ST2   = OFF_ST1 + 256;
static constexpr size_t OFF_SC1   = OFF_ST2 + 256;            // [128]
static constexpr size_t OFF_SH1   = OFF_SC1 + 128;
static constexpr size_t OFF_SC2   = OFF_SH1 + 128;
static constexpr size_t OFF_SH2   = OFF_SC2 + 128;
static constexpr size_t OFF_POOL  = OFF_SH2 + 128;            // [B*HC]
static constexpr size_t OFF_CNT   = OFF_POOL+ (size_t)BB*HC;  // [B]
static constexpr size_t OFF_ZEND  = OFF_CNT + BB;             // end of zeroed float region
// ints (after float region)
static constexpr size_t IOFF_DEG  = 0;                        // [N]  (zeroed)
static constexpr size_t IOFF_ROWP = IOFF_DEG  + NN;           // [N+1]
static constexpr size_t IOFF_CUR  = IOFF_ROWP + NN + 1;       // [N]
static constexpr size_t IOFF_BSUM = IOFF_CUR  + NN;           // [NBLK_SCAN]
static constexpr size_t IOFF_BOFS = IOFF_BSUM + NBLK_SCAN;    // [NBLK_SCAN]
static constexpr size_t IOFF_ESRC = IOFF_BOFS + NBLK_SCAN;    // [ETOT]
static constexpr size_t IOFF_HB   = (IOFF_ESRC + ETOT + 3) & ~(size_t)3;  // [N*64] uints
static constexpr size_t IOFF_WF1  = IOFF_HB + (size_t)NN*64;  // [512*64] ints
static constexpr size_t IOFF_WF2  = IOFF_WF1 + (size_t)IN_C*64; // [128*64] ints
static constexpr size_t IOFF_END  = IOFF_WF2 + (size_t)HC*64;

extern "C" void kernel_launch(void* const* d_in, const int* in_sizes, int n_in,
                              void* d_out, int out_size, void* d_ws, size_t ws_size,
                              hipStream_t stream)
{
    const float* x       = (const float*)d_in[0];
    const int*   ei      = (const int*)  d_in[1];
    const int*   batch   = (const int*)  d_in[2];
    const float* W1      = (const float*)d_in[3];
    const float* atts1   = (const float*)d_in[4];
    const float* attd1   = (const float*)d_in[5];
    const float* gamma1  = (const float*)d_in[7];
    const float* beta1   = (const float*)d_in[8];
    const float* W2      = (const float*)d_in[9];
    const float* atts2   = (const float*)d_in[10];
    const float* attd2   = (const float*)d_in[11];
    const float* gamma2  = (const float*)d_in[13];
    const float* beta2   = (const float*)d_in[14];
    const float* Wlin    = (const float*)d_in[15];
    const float* blin    = (const float*)d_in[16];
    float* outp = (float*)d_out;

    float* ws    = (float*)d_ws;
    float* out   = ws + OFF_OUT;
    float* as_   = ws + OFF_AS;
    float* ad_   = ws + OFF_AD;
    float* st1   = ws + OFF_ST1;
    float* st2   = ws + OFF_ST2;
    float* sc1   = ws + OFF_SC1;
    float* sh1   = ws + OFF_SH1;
    float* sc2   = ws + OFF_SC2;
    float* sh2   = ws + OFF_SH2;
    float* pool  = ws + OFF_POOL;
    float* cnt   = ws + OFF_CNT;

    int* iws  = (int*)(ws + OFF_ZEND);
    int* deg  = iws + IOFF_DEG;
    int* rowp = iws + IOFF_ROWP;
    int* curp = iws + IOFF_CUR;
    int* bsum = iws + IOFF_BSUM;
    int* bofs = iws + IOFF_BOFS;
    int* esrc = iws + IOFF_ESRC;
    unsigned* hb = (unsigned*)(iws + IOFF_HB);
    unsigned short* Wf1 = (unsigned short*)(iws + IOFF_WF1);
    unsigned short* Wf2 = (unsigned short*)(iws + IOFF_WF2);

    const int EDGE_BLK  = (ETOT + 255) / 256;
    const int GEMM_BLK  = (NN + 63) / 64;        // 782
    const int WAVE_BLK  = (NN + 3) / 4;          // 1 wave per node, 4 waves/block
    const int POOL_BLK  = (NN + 63) / 64;        // 782: 64 rows/block

    // zero: bn-stats/pool/cnt float region + deg
    hipMemsetAsync(st1, 0, (OFF_ZEND - OFF_ST1) * sizeof(float), stream);
    hipMemsetAsync(deg, 0, NN * sizeof(int), stream);

    // ----- weight fragment packs + CSR build (shared by both layers) -----
    wfrag_kernel<<<(IN_C * 16 + 255) / 256, 256, 0, stream>>>(W1, Wf1, IN_C);
    wfrag_kernel<<<(HC   * 16 + 255) / 256, 256, 0, stream>>>(W2, Wf2, HC);
    deg_kernel<<<EDGE_BLK, 256, 0, stream>>>(ei, deg);
    bsum_kernel<<<NBLK_SCAN, 256, 0, stream>>>(deg, bsum);
    bscan_kernel<<<1, 256, 0, stream>>>(bsum, bofs, rowp);
    bapply_kernel<<<NBLK_SCAN, 256, 0, stream>>>(deg, bofs, rowp, curp);
    scatter_kernel<<<EDGE_BLK, 256, 0, stream>>>(ei, curp, esrc);

    // ----- layer 1 (GEMM + fused alpha + bf16 pack) -----
    mfma_gemm_kernel<false><<<GEMM_BLK, 256, 0, stream>>>(
        x, Wf1, atts1, attd1, hb, as_, ad_, IN_C, nullptr, nullptr);
    gat_agg_kernel<<<WAVE_BLK, 256, 0, stream>>>(rowp, esrc, as_, ad_, hb, out);
    bn_stats_kernel<<<512, 256, 0, stream>>>(out, st1);
    bn_params_kernel<<<1, 128, 0, stream>>>(st1, gamma1, beta1, sc1, sh1);

    // ----- layer 2 (BN1-affine+ReLU fused into GEMM2 A-load) -----
    mfma_gemm_kernel<true><<<GEMM_BLK, 256, 0, stream>>>(
        out, Wf2, atts2, attd2, hb, as_, ad_, HC, sc1, sh1);
    gat_agg_kernel<<<WAVE_BLK, 256, 0, stream>>>(rowp, esrc, as_, ad_, hb, out);
    bn_stats_kernel<<<512, 256, 0, stream>>>(out, st2);
    bn_params_kernel<<<1, 128, 0, stream>>>(st2, gamma2, beta2, sc2, sh2);

    // ----- pool + final linear -----
    pool_kernel<<<POOL_BLK, 256, 0, stream>>>(out, sc2, sh2, batch, pool, cnt);
    final_kernel<<<1, 128, 0, stream>>>(pool, cnt, Wlin, blin, outp);
}

// Round 7
// 520.372 us; speedup vs baseline: 2.9496x; 1.0167x over previous
//
#include <hip/hip_runtime.h>
#include <hip/hip_bf16.h>
#include <cstdint>
#include <cstddef>

// Problem constants (match reference)
#define NN      50000
#define IN_C    512
#define EE      800000
#define ETOT    850000      // E + N self-loops
#define HH      2
#define CC      64
#define HC      128
#define BB      64
#define OUTC    2
#define NEG_SLOPE 0.2f
#define BN_EPS  1e-5f

#define NBLK_SCAN ((NN + 255) / 256)   // 196

typedef __bf16 bf16x8 __attribute__((ext_vector_type(8)));
typedef float  f32x4  __attribute__((ext_vector_type(4)));

__device__ __forceinline__ unsigned f2bf(float f) {
    __bf16 b = (__bf16)f;                      // RNE convert
    return (unsigned)__builtin_bit_cast(unsigned short, b);
}

__device__ __forceinline__ void edge_sd(const int* __restrict__ ei, int e, int& s, int& d) {
    if (e < EE) { s = ei[e]; d = ei[EE + e]; }
    else        { s = e - EE; d = e - EE; }
}

// ================= CSR build (graph fixed; built once per launch, reused by both layers) =================
__global__ __launch_bounds__(256) void deg_kernel(const int* __restrict__ ei, int* __restrict__ deg)
{
    int e = blockIdx.x * 256 + threadIdx.x;
    if (e >= ETOT) return;
    int d = (e < EE) ? ei[EE + e] : (e - EE);
    atomicAdd(&deg[d], 1);
}

// --- hierarchical scan ---
__global__ __launch_bounds__(256) void bsum_kernel(const int* __restrict__ deg, int* __restrict__ bsum)
{
    int i = blockIdx.x * 256 + threadIdx.x;
    int v = (i < NN) ? deg[i] : 0;
    int lane = threadIdx.x & 63, wv = threadIdx.x >> 6;
#pragma unroll
    for (int o = 32; o > 0; o >>= 1) v += __shfl_down(v, o);
    __shared__ int ws[4];
    if (lane == 0) ws[wv] = v;
    __syncthreads();
    if (threadIdx.x == 0) bsum[blockIdx.x] = ws[0] + ws[1] + ws[2] + ws[3];
}

__global__ __launch_bounds__(256) void bscan_kernel(
    const int* __restrict__ bsum, int* __restrict__ bofs, int* __restrict__ rowp)
{
    int t = threadIdx.x;
    int lane = t & 63, wv = t >> 6;
    int v = (t < NBLK_SCAN) ? bsum[t] : 0;
    int x = v;
#pragma unroll
    for (int o = 1; o < 64; o <<= 1) {
        int y = __shfl_up(x, o);
        if (lane >= o) x += y;
    }
    __shared__ int ws[4];
    if (lane == 63) ws[wv] = x;
    __syncthreads();
    int wo = 0;
#pragma unroll
    for (int w = 0; w < 4; ++w) if (w < wv) wo += ws[w];
    if (t < NBLK_SCAN) bofs[t] = x + wo - v;     // exclusive
    if (t == 0) rowp[NN] = ETOT;
}

__global__ __launch_bounds__(256) void bapply_kernel(
    const int* __restrict__ deg, const int* __restrict__ bofs,
    int* __restrict__ rowp, int* __restrict__ cur)
{
    int i = blockIdx.x * 256 + threadIdx.x;
    int v = (i < NN) ? deg[i] : 0;
    int lane = threadIdx.x & 63, wv = threadIdx.x >> 6;
    int x = v;
#pragma unroll
    for (int o = 1; o < 64; o <<= 1) {
        int y = __shfl_up(x, o);
        if (lane >= o) x += y;
    }
    __shared__ int ws[4];
    if (lane == 63) ws[wv] = x;
    __syncthreads();
    int wo = 0;
#pragma unroll
    for (int w = 0; w < 4; ++w) if (w < wv) wo += ws[w];
    if (i < NN) {
        int r = bofs[blockIdx.x] + x + wo - v;   // exclusive global
        rowp[i] = r; cur[i] = r;
    }
}

__global__ __launch_bounds__(256) void scatter_kernel(
    const int* __restrict__ ei, int* __restrict__ cur, int* __restrict__ esrc)
{
    int e = blockIdx.x * 256 + threadIdx.x;
    if (e >= ETOT) return;
    int s, d; edge_sd(ei, e, s, d);
    int pos = atomicAdd(&cur[d], 1);
    esrc[pos] = s;
}

// ================= W -> bf16 MFMA fragment order =================
__global__ __launch_bounds__(256) void wfrag_kernel(
    const float* __restrict__ W, unsigned short* __restrict__ Wf, int K)
{
    int t = blockIdx.x * 256 + threadIdx.x;       // t = frag*64 + lane
    if (t >= K * 16) return;                      // (K/32)*8*64 == K*16
    int lane = t & 63, frag = t >> 6;
    int kblk = frag >> 3, nt = frag & 7;
    int quad = lane >> 4, ln = lane & 15;
    int kbase = kblk * 32 + quad * 8;
    int n = nt * 16 + ln;
    unsigned short u[8];
#pragma unroll
    for (int j = 0; j < 8; ++j)
        u[j] = (unsigned short)f2bf(W[(size_t)(kbase + j) * HC + n]);
    ushort4 a; a.x = u[0]; a.y = u[1]; a.z = u[2]; a.w = u[3];
    ushort4 b; b.x = u[4]; b.y = u[5]; b.z = u[6]; b.w = u[7];
    *(ushort4*)(Wf + (size_t)t * 8)     = a;
    *(ushort4*)(Wf + (size_t)t * 8 + 4) = b;
}

// ================= barrier-free per-wave MFMA GEMM + fused alpha + bf16 pack =================
// Each wave owns 16 rows x 128 cols. Lane (quad,ln) loads its own A-frag fp32 directly
// (A[row=ln][k=quad*8..+8], 32B/lane — same coalescing as a staged load), converts in
// registers, streams B-frags from pre-packed Wf (L2-resident). No LDS, no __syncthreads:
// waves decouple, latency hidden by TLP + manual next-load software pipeline.
template<bool AFFINE>
__global__ __launch_bounds__(256) void mfma_gemm_kernel(
    const float* __restrict__ A, const unsigned short* __restrict__ Wf,
    const float* __restrict__ atts, const float* __restrict__ attd,
    unsigned* __restrict__ hb, float* __restrict__ as_, float* __restrict__ ad_,
    int K, const float* __restrict__ sc, const float* __restrict__ sh)
{
    const int tid  = threadIdx.x;
    const int wave = tid >> 6, lane = tid & 63;
    const int quad = lane >> 4, ln = lane & 15;
    const int m0 = blockIdx.x * 64;
    const int myrow = m0 + wave * 16 + ln;        // row this lane's A-frag comes from
    const bool rok = (myrow < NN);
    const float* arow = A + (size_t)(rok ? myrow : 0) * K + quad * 8;

    f32x4 acc[8];
#pragma unroll
    for (int nt = 0; nt < 8; ++nt) acc[nt] = (f32x4){0.f, 0.f, 0.f, 0.f};

    const int nsteps = K >> 5;

    // prologue: A regs for ks=0
    float4 a0 = make_float4(0.f,0.f,0.f,0.f), a1 = a0;
    if (rok) { a0 = *(const float4*)arow; a1 = *(const float4*)(arow + 4); }

    for (int ks = 0; ks < nsteps; ++ks) {
        // B-frags for this step (independent loads, issue first)
        const unsigned short* wfp = Wf + (size_t)ks * 4096 + lane * 8;
        bf16x8 bfr[8];
#pragma unroll
        for (int nt = 0; nt < 8; ++nt) bfr[nt] = *(const bf16x8*)(wfp + nt * 512);

        // convert this step's A-frag (loaded last iteration)
        float va[8] = {a0.x, a0.y, a0.z, a0.w, a1.x, a1.y, a1.z, a1.w};
        if (AFFINE) {
            int kk = ks * 32 + quad * 8;
#pragma unroll
            for (int j = 0; j < 8; ++j)
                va[j] = fmaxf(fmaf(sc[kk + j], va[j], sh[kk + j]), 0.f);
        }
        union { bf16x8 v; unsigned short u[8]; } af;
#pragma unroll
        for (int j = 0; j < 8; ++j) af.u[j] = (unsigned short)f2bf(va[j]);

        // issue next step's A loads (hidden behind the MFMAs)
        if (ks + 1 < nsteps && rok) {
            const float* nxt = arow + (size_t)(ks + 1) * 32;
            a0 = *(const float4*)nxt; a1 = *(const float4*)(nxt + 4);
        }

#pragma unroll
        for (int nt = 0; nt < 8; ++nt)
            acc[nt] = __builtin_amdgcn_mfma_f32_16x16x32_bf16(af.v, bfr[nt], acc[nt], 0, 0, 0);
    }

    // epilogue: pack bf16 pairs + fused attention logits; C/D layout col=ln, row=quad*4+r
    const int mbase = m0 + wave * 16 + quad * 4;
#pragma unroll
    for (int r = 0; r < 4; ++r) {
        int m = mbase + r;
        bool ok = (m < NN);
        float ps0 = 0.f, ps1 = 0.f, pd0 = 0.f, pd1 = 0.f;
#pragma unroll
        for (int nt = 0; nt < 8; ++nt) {
            float v  = acc[nt][r];
            float wsv = atts[nt * 16 + ln], wd = attd[nt * 16 + ln];
            if (nt < 4) { ps0 = fmaf(v, wsv, ps0); pd0 = fmaf(v, wd, pd0); }
            else        { ps1 = fmaf(v, wsv, ps1); pd1 = fmaf(v, wd, pd1); }
        }
#pragma unroll
        for (int nt = 0; nt < 4; ++nt) {
            unsigned pk = f2bf(acc[nt][r]) | (f2bf(acc[nt + 4][r]) << 16);
            if (ok) hb[(size_t)m * 64 + nt * 16 + ln] = pk;
        }
#pragma unroll
        for (int o = 8; o > 0; o >>= 1) {
            ps0 += __shfl_down(ps0, o); ps1 += __shfl_down(ps1, o);
            pd0 += __shfl_down(pd0, o); pd1 += __shfl_down(pd1, o);
        }
        if (ok && ln == 0) {
            *(float2*)&as_[m * 2] = make_float2(ps0, ps1);
            *(float2*)&ad_[m * 2] = make_float2(pd0, pd1);
        }
    }
}

// ================= fused segment-softmax + aggregate: one wave per dst node =================
__global__ __launch_bounds__(256) void gat_agg_kernel(
    const int* __restrict__ rowp, const int* __restrict__ esrc,
    const float* __restrict__ as_, const float* __restrict__ ad_,
    const unsigned* __restrict__ hb, float* __restrict__ out)
{
    int node = (blockIdx.x * 256 + threadIdx.x) >> 6;
    int lane = threadIdx.x & 63;
    if (node >= NN) return;
    int beg = rowp[node], end = rowp[node + 1];
    float ad0 = ad_[node * 2 + 0], ad1 = ad_[node * 2 + 1];

    float l0 = 0.f, l1 = 0.f, a0 = 0.f, a1 = 0.f;

    for (int j0 = beg; j0 < end; j0 += 64) {
        int nj = min(64, end - j0);
        int   sl  = 0;
        float es0 = 0.f, es1 = 0.f;
        if (j0 + lane < end) {
            sl = esrc[j0 + lane];
            float2 t = *(const float2*)&as_[sl * 2];
            es0 = t.x; es1 = t.y;
        }
        for (int j = 0; j < nj; ++j) {
            int   s  = __shfl(sl, j);
            float e0 = __shfl(es0, j) + ad0; e0 = fmaxf(e0, NEG_SLOPE * e0);
            float e1 = __shfl(es1, j) + ad1; e1 = fmaxf(e1, NEG_SLOPE * e1);
            float p0 = __expf(e0), p1 = __expf(e1);
            unsigned u = hb[(size_t)s * 64 + lane];
            float h0 = __uint_as_float(u << 16);
            float h1 = __uint_as_float(u & 0xffff0000u);
            l0 += p0; l1 += p1;
            a0 = fmaf(p0, h0, a0); a1 = fmaf(p1, h1, a1);
        }
    }
    out[(size_t)node * HC + lane]      = a0 / l0;
    out[(size_t)node * HC + 64 + lane] = a1 / l1;
}

// ================= BN stats =================
__global__ __launch_bounds__(256) void bn_stats_kernel(
    const float* __restrict__ x, float* __restrict__ stats)
{
    int c = threadIdx.x & 127;
    int half = threadIdx.x >> 7;
    float s = 0.f, sq = 0.f;
    for (int r = blockIdx.x * 2 + half; r < NN; r += gridDim.x * 2) {
        float v = x[(size_t)r * HC + c];
        s += v; sq += v * v;
    }
    __shared__ float ls[256], lq[256];
    ls[threadIdx.x] = s; lq[threadIdx.x] = sq;
    __syncthreads();
    if (half == 0) {
        s += ls[threadIdx.x + 128];
        sq += lq[threadIdx.x + 128];
        atomicAdd(&stats[c], s);
        atomicAdd(&stats[128 + c], sq);
    }
}

__global__ void bn_params_kernel(
    const float* __restrict__ stats, const float* __restrict__ gamma,
    const float* __restrict__ beta, float* __restrict__ sc, float* __restrict__ sh)
{
    int c = threadIdx.x;
    const float inv_n = 1.0f / (float)NN;
    float mu = stats[c] * inv_n;
    float var = stats[128 + c] * inv_n - mu * mu;
    float rs = rsqrtf(var + BN_EPS);
    float s = gamma[c] * rs;
    sc[c] = s;
    sh[c] = beta[c] - mu * s;
}

// ================= pool: 64 rows/block (782 blocks), flush-on-graph-change =================
__global__ __launch_bounds__(256) void pool_kernel(
    const float* __restrict__ x, const float* __restrict__ sc,
    const float* __restrict__ sh, const int* __restrict__ batch,
    float* __restrict__ pool, float* __restrict__ cnt)
{
    int c = threadIdx.x & 127;
    int half = threadIdx.x >> 7;
    int r0 = blockIdx.x * 64;
    int rend = min(r0 + 64, NN);
    float s = sc[c], b = sh[c];
    int cur = -1; float acc = 0.f, ccount = 0.f;
    for (int r = r0 + half; r < rend; r += 2) {
        int g = batch[r];
        if (g != cur) {
            if (cur >= 0) {
                atomicAdd(&pool[cur * HC + c], acc);
                if (c == 0) atomicAdd(&cnt[cur], ccount);
            }
            cur = g; acc = 0.f; ccount = 0.f;
        }
        float v = x[(size_t)r * HC + c];
        acc += fmaxf(fmaf(s, v, b), 0.f);
        ccount += 1.f;
    }
    if (cur >= 0) {
        atomicAdd(&pool[cur * HC + c], acc);
        if (c == 0) atomicAdd(&cnt[cur], ccount);
    }
}

// ================= final linear: [64,128]@[128,2] + blin =================
__global__ void final_kernel(
    const float* __restrict__ pool, const float* __restrict__ cnt,
    const float* __restrict__ Wlin, const float* __restrict__ blin,
    float* __restrict__ outp)
{
    int t = threadIdx.x;               // 128 threads
    int b = t >> 1, oc = t & 1;
    float inv = 1.f / fmaxf(cnt[b], 1.f);
    float s = blin[oc];
    for (int c = 0; c < HC; ++c)
        s += pool[b * HC + c] * inv * Wlin[c * 2 + oc];
    outp[b * 2 + oc] = s;
}

// ================= workspace layout =================
// floats
static constexpr size_t OFF_OUT   = 0;                        // [N*HC]
static constexpr size_t OFF_AS    = OFF_OUT + (size_t)NN*HC;  // [N*2]
static constexpr size_t OFF_AD    = OFF_AS  + (size_t)NN*HH;
static constexpr size_t OFF_ST1   = OFF_AD  + (size_t)NN*HH;  // zero from here: [256]
static constexpr size_t OFF_ST2   = OFF_ST1 + 256;
static constexpr size_t OFF_SC1   = OFF_ST2 + 256;            // [128]
static constexpr size_t OFF_SH1   = OFF_SC1 + 128;
static constexpr size_t OFF_SC2   = OFF_SH1 + 128;
static constexpr size_t OFF_SH2   = OFF_SC2 + 128;
static constexpr size_t OFF_POOL  = OFF_SH2 + 128;            // [B*HC]
static constexpr size_t OFF_CNT   = OFF_POOL+ (size_t)BB*HC;  // [B]
static constexpr size_t OFF_ZEND  = OFF_CNT + BB;             // end of zeroed float region
// ints (after float region)
static constexpr size_t IOFF_DEG  = 0;                        // [N]  (zeroed)
static constexpr size_t IOFF_ROWP = IOFF_DEG  + NN;           // [N+1]
static constexpr size_t IOFF_CUR  = IOFF_ROWP + NN + 1;       // [N]
static constexpr size_t IOFF_BSUM = IOFF_CUR  + NN;           // [NBLK_SCAN]
static constexpr size_t IOFF_BOFS = IOFF_BSUM + NBLK_SCAN;    // [NBLK_SCAN]
static constexpr size_t IOFF_ESRC = IOFF_BOFS + NBLK_SCAN;    // [ETOT]
static constexpr size_t IOFF_HB   = (IOFF_ESRC + ETOT + 3) & ~(size_t)3;  // [N*64] uints
static constexpr size_t IOFF_WF1  = IOFF_HB + (size_t)NN*64;  // [512*64] ints
static constexpr size_t IOFF_WF2  = IOFF_WF1 + (size_t)IN_C*64; // [128*64] ints
static constexpr size_t IOFF_END  = IOFF_WF2 + (size_t)HC*64;

extern "C" void kernel_launch(void* const* d_in, const int* in_sizes, int n_in,
                              void* d_out, int out_size, void* d_ws, size_t ws_size,
                              hipStream_t stream)
{
    const float* x       = (const float*)d_in[0];
    const int*   ei      = (const int*)  d_in[1];
    const int*   batch   = (const int*)  d_in[2];
    const float* W1      = (const float*)d_in[3];
    const float* atts1   = (const float*)d_in[4];
    const float* attd1   = (const float*)d_in[5];
    const float* gamma1  = (const float*)d_in[7];
    const float* beta1   = (const float*)d_in[8];
    const float* W2      = (const float*)d_in[9];
    const float* atts2   = (const float*)d_in[10];
    const float* attd2   = (const float*)d_in[11];
    const float* gamma2  = (const float*)d_in[13];
    const float* beta2   = (const float*)d_in[14];
    const float* Wlin    = (const float*)d_in[15];
    const float* blin    = (const float*)d_in[16];
    float* outp = (float*)d_out;

    float* ws    = (float*)d_ws;
    float* out   = ws + OFF_OUT;
    float* as_   = ws + OFF_AS;
    float* ad_   = ws + OFF_AD;
    float* st1   = ws + OFF_ST1;
    float* st2   = ws + OFF_ST2;
    float* sc1   = ws + OFF_SC1;
    float* sh1   = ws + OFF_SH1;
    float* sc2   = ws + OFF_SC2;
    float* sh2   = ws + OFF_SH2;
    float* pool  = ws + OFF_POOL;
    float* cnt   = ws + OFF_CNT;

    int* iws  = (int*)(ws + OFF_ZEND);
    int* deg  = iws + IOFF_DEG;
    int* rowp = iws + IOFF_ROWP;
    int* curp = iws + IOFF_CUR;
    int* bsum = iws + IOFF_BSUM;
    int* bofs = iws + IOFF_BOFS;
    int* esrc = iws + IOFF_ESRC;
    unsigned* hb = (unsigned*)(iws + IOFF_HB);
    unsigned short* Wf1 = (unsigned short*)(iws + IOFF_WF1);
    unsigned short* Wf2 = (unsigned short*)(iws + IOFF_WF2);

    const int EDGE_BLK  = (ETOT + 255) / 256;
    const int GEMM_BLK  = (NN + 63) / 64;        // 782
    const int WAVE_BLK  = (NN + 3) / 4;          // 1 wave per node, 4 waves/block
    const int POOL_BLK  = (NN + 63) / 64;        // 782: 64 rows/block

    // zero: bn-stats/pool/cnt float region + deg
    hipMemsetAsync(st1, 0, (OFF_ZEND - OFF_ST1) * sizeof(float), stream);
    hipMemsetAsync(deg, 0, NN * sizeof(int), stream);

    // ----- weight fragment packs + CSR build (shared by both layers) -----
    wfrag_kernel<<<(IN_C * 16 + 255) / 256, 256, 0, stream>>>(W1, Wf1, IN_C);
    wfrag_kernel<<<(HC   * 16 + 255) / 256, 256, 0, stream>>>(W2, Wf2, HC);
    deg_kernel<<<EDGE_BLK, 256, 0, stream>>>(ei, deg);
    bsum_kernel<<<NBLK_SCAN, 256, 0, stream>>>(deg, bsum);
    bscan_kernel<<<1, 256, 0, stream>>>(bsum, bofs, rowp);
    bapply_kernel<<<NBLK_SCAN, 256, 0, stream>>>(deg, bofs, rowp, curp);
    scatter_kernel<<<EDGE_BLK, 256, 0, stream>>>(ei, curp, esrc);

    // ----- layer 1 (GEMM + fused alpha + bf16 pack) -----
    mfma_gemm_kernel<false><<<GEMM_BLK, 256, 0, stream>>>(
        x, Wf1, atts1, attd1, hb, as_, ad_, IN_C, nullptr, nullptr);
    gat_agg_kernel<<<WAVE_BLK, 256, 0, stream>>>(rowp, esrc, as_, ad_, hb, out);
    bn_stats_kernel<<<512, 256, 0, stream>>>(out, st1);
    bn_params_kernel<<<1, 128, 0, stream>>>(st1, gamma1, beta1, sc1, sh1);

    // ----- layer 2 (BN1-affine+ReLU fused into GEMM2 A-load) -----
    mfma_gemm_kernel<true><<<GEMM_BLK, 256, 0, stream>>>(
        out, Wf2, atts2, attd2, hb, as_, ad_, HC, sc1, sh1);
    gat_agg_kernel<<<WAVE_BLK, 256, 0, stream>>>(rowp, esrc, as_, ad_, hb, out);
    bn_stats_kernel<<<512, 256, 0, stream>>>(out, st2);
    bn_params_kernel<<<1, 128, 0, stream>>>(st2, gamma2, beta2, sc2, sh2);

    // ----- pool + final linear -----
    pool_kernel<<<POOL_BLK, 256, 0, stream>>>(out, sc2, sh2, batch, pool, cnt);
    final_kernel<<<1, 128, 0, stream>>>(pool, cnt, Wlin, blin, outp);
}